// Round 2
// baseline (250.181 us; speedup 1.0000x reference)
//
#include <hip/hip_runtime.h>
#include <math.h>

// ---------------------------------------------------------------------------
// AttentionLayer: out = softmax(mask(q k^T * scale)) @ v,  q/k/v = x@W + b
// B=4, T=2048, C=H=768.  bf16 MFMA (16x16x32), fp32 accumulate.
// R3: gemm_core = unroll-2 STATIC double-buffer.
// R5 (this round): gemm_core -> 4-slot circular pipeline, depth-3 prefetch,
//     counted vmcnt (T4): one raw s_barrier per k-tile, s_waitcnt vmcnt(8)
//     steady-state (prefetched loads stay in flight ACROSS the barrier),
//     drain 8/8/4/0 only in the last group.  Group-of-4 unroll keeps all LDS
//     slot addresses compile-time (R1 lesson: dynamic toggle = VALU blowup).
//     LDS 32KB -> 64KB (2 blocks/CU instead of 3; m201-proven TLP->ILP trade).
// ---------------------------------------------------------------------------

#define BB 4
#define TT 2048
#define CC 768

typedef __bf16 bf16_t;
typedef __bf16 bf16x8 __attribute__((ext_vector_type(8)));
typedef _Float16 half8 __attribute__((ext_vector_type(8)));
typedef float f32x4 __attribute__((ext_vector_type(4)));

// ---------------------------------------------------------------------------
// async global->LDS 16B copy (wave-uniform LDS base + lane*16 implicit)
// ---------------------------------------------------------------------------
__device__ __forceinline__ void async_load16(void* lds, const void* g) {
  __builtin_amdgcn_global_load_lds(
      (const __attribute__((address_space(1))) void*)g,
      (__attribute__((address_space(3))) void*)lds, 16, 0, 0);
}

// Stage a 128x32 bf16 tile (row-major, row stride ld elements) into LDS.
// LDS layout: row-major 128x32, 8-elem chunks XOR-swizzled within a row:
// physical chunk p of row r holds logical chunk q = p ^ (r & 3).
// 2 global_load_lds per thread per tile (4 per k-tile incl. A and B).
__device__ __forceinline__ void stage_tile(const bf16_t* __restrict__ g0,
                                           int ld, bf16_t* lds, int t) {
  int w = t >> 6, l = t & 63;
#pragma unroll
  for (int i = 0; i < 2; ++i) {
    int c = i * 256 + w * 64 + l;   // linear 16B-chunk id in LDS
    int row = c >> 2;
    int p = c & 3;
    int q = p ^ (row & 3);          // logical chunk to fetch
    async_load16(lds + i * 2048 + w * 512,  // wave-uniform base (elements)
                 g0 + row * ld + q * 8);
  }
}

// Read one MFMA fragment (8 bf16, 16B) for logical (row r, k-chunk q).
__device__ __forceinline__ bf16x8 read_frag(const bf16_t* lds, int r, int q) {
  int p = q ^ (r & 3);
  return *(const bf16x8*)(lds + r * 32 + p * 8);
}

// One 128x128x32 MFMA step from a published LDS buffer pair.
__device__ __forceinline__ void mfma_tile(const bf16_t* Ab, const bf16_t* Bb,
                                          int wr, int wc, int l,
                                          f32x4 acc[4][4]) {
  bf16x8 af[4], bfr[4];
  int q = l >> 4;
#pragma unroll
  for (int i = 0; i < 4; ++i) {
    af[i] = read_frag(Ab, wr + i * 16 + (l & 15), q);
    bfr[i] = read_frag(Bb, wc + i * 16 + (l & 15), q);
  }
#pragma unroll
  for (int mi = 0; mi < 4; ++mi)
#pragma unroll
    for (int ni = 0; ni < 4; ++ni)
      acc[mi][ni] = __builtin_amdgcn_mfma_f32_16x16x32_bf16(
          af[mi], bfr[ni], acc[mi][ni], 0, 0, 0);
}

// ---------------------------------------------------------------------------
// Core: C[128x128] += A[128xK] * B^T.  kTiles must be a multiple of 4 (>=4).
//
// 4-slot circular pipeline, depth-3 prefetch, counted vmcnt:
//   body(kt):  s_waitcnt vmcnt(8)   // kt's own 4 loads (oldest) complete;
//                                   // kt+1/kt+2 prefetches stay IN FLIGHT
//              s_barrier            // all waves finished staging kt AND
//                                   // finished reading kt-1 (same slot as
//                                   // the stage below)
//              stage(kt+3) -> slot (kt+3)&3
//              mfma(slot kt&3)
// Safety: read slot kt&3 is distinct from in-flight write slots
// (kt+1..kt+3)&3.  Slot (kt+3)&3 == slot of kt-1, whose ds_reads all feed
// MFMAs issued before the barrier, so they are drained at wave arrival.
// asm "memory" clobbers + sched_barrier(0) pin LDS ops across the raw
// barrier (the raw builtin has no memory semantics of its own).
// ---------------------------------------------------------------------------
__device__ __forceinline__ void gemm_core(const bf16_t* __restrict__ A, int lda,
                                          const bf16_t* __restrict__ B, int ldb,
                                          int kTiles, bf16_t (*As)[4096],
                                          bf16_t (*Bs)[4096],
                                          f32x4 acc[4][4]) {
  int t = threadIdx.x;
  int l = t & 63;
  int w = t >> 6;
  int wr = (w >> 1) * 64;  // wave row offset in 128-tile
  int wc = (w & 1) * 64;   // wave col offset

  // prologue: stage tiles 0,1,2 -> slots 0,1,2 (12 loads/thread in flight)
  stage_tile(A, lda, As[0], t);
  stage_tile(B, ldb, Bs[0], t);
  stage_tile(A + 32, lda, As[1], t);
  stage_tile(B + 32, ldb, Bs[1], t);
  stage_tile(A + 64, lda, As[2], t);
  stage_tile(B + 64, ldb, Bs[2], t);

#define GEMM_BODY(J, WAITN, DO_STAGE)                                  \
  {                                                                    \
    asm volatile("s_waitcnt vmcnt(" #WAITN ")" ::: "memory");          \
    __builtin_amdgcn_s_barrier();                                      \
    __builtin_amdgcn_sched_barrier(0);                                 \
    if (DO_STAGE) {                                                    \
      stage_tile(A + (kt + (J) + 3) * 32, lda, As[((J) + 3) & 3], t);  \
      stage_tile(B + (kt + (J) + 3) * 32, ldb, Bs[((J) + 3) & 3], t);  \
    }                                                                  \
    mfma_tile(As[(J)], Bs[(J)], wr, wc, l, acc);                       \
  }

  int kt = 0;
  for (; kt + 4 < kTiles; kt += 4) {
    GEMM_BODY(0, 8, true)
    GEMM_BODY(1, 8, true)
    GEMM_BODY(2, 8, true)
    GEMM_BODY(3, 8, true)
  }
  // final group (kt == kTiles-4): only first body has a tile left to stage
  GEMM_BODY(0, 8, true)   // stages tile kTiles-1
  GEMM_BODY(1, 8, false)  // 8 outstanding; wait is exact for kt+1
  GEMM_BODY(2, 4, false)
  GEMM_BODY(3, 0, false)
#undef GEMM_BODY
}

// C/D layout (m89-verified): col = lane&15, row = (lane>>4)*4 + reg.

// ---------------------------------------------------------------------------
// Kernel 1: cast x (fp32) -> bf16, 8 elems/thread
// ---------------------------------------------------------------------------
__global__ __launch_bounds__(256) void cast_x_kernel(
    const float* __restrict__ x, bf16_t* __restrict__ xbf) {
  int i = blockIdx.x * 256 + threadIdx.x;
  const float4* xin = (const float4*)x;
  float4 a = xin[i * 2];
  float4 b = xin[i * 2 + 1];
  bf16_t tmp[8];
  tmp[0] = (bf16_t)a.x; tmp[1] = (bf16_t)a.y;
  tmp[2] = (bf16_t)a.z; tmp[3] = (bf16_t)a.w;
  tmp[4] = (bf16_t)b.x; tmp[5] = (bf16_t)b.y;
  tmp[6] = (bf16_t)b.z; tmp[7] = (bf16_t)b.w;
  *(uint4*)(xbf + (size_t)i * 8) = *(const uint4*)tmp;
}

// ---------------------------------------------------------------------------
// Kernel 2: transpose+cast the three weight matrices [C][H] -> bf16 [H][C]
// ---------------------------------------------------------------------------
__global__ __launch_bounds__(256) void transpose_w_kernel(
    const float* __restrict__ Wq, const float* __restrict__ Wk,
    const float* __restrict__ Wv, bf16_t* __restrict__ wt) {
  int z = blockIdx.z;
  const float* W = (z == 0) ? Wq : (z == 1) ? Wk : Wv;
  bf16_t* out = wt + (size_t)z * CC * CC;
  __shared__ float tile[32][33];
  int tx = threadIdx.x;  // 0..31
  int ty = threadIdx.y;  // 0..7
  int n0 = blockIdx.x * 32;
  int c0 = blockIdx.y * 32;
#pragma unroll
  for (int k = 0; k < 4; ++k)
    tile[ty + k * 8][tx] = W[(size_t)(c0 + ty + k * 8) * CC + n0 + tx];
  __syncthreads();
#pragma unroll
  for (int k = 0; k < 4; ++k)
    out[(size_t)(n0 + ty + k * 8) * CC + c0 + tx] =
        (bf16_t)tile[tx][ty + k * 8];
}

// ---------------------------------------------------------------------------
// Kernel 3: QKV GEMM.  z=0: q (scaled by H^-1/2), z=1: k, z=2: v transposed.
// ---------------------------------------------------------------------------
__global__ __launch_bounds__(256) void qkv_gemm_kernel(
    const bf16_t* __restrict__ xbf, const bf16_t* __restrict__ wt,
    const float* __restrict__ bq, const float* __restrict__ bk,
    const float* __restrict__ bv, bf16_t* __restrict__ qb,
    bf16_t* __restrict__ kb, bf16_t* __restrict__ vt) {
  __shared__ bf16_t As[4][4096], Bs[4][4096];
  int n0 = blockIdx.x * 128;
  int m0 = blockIdx.y * 128;
  int z = blockIdx.z;

  f32x4 acc[4][4];
#pragma unroll
  for (int i = 0; i < 4; ++i)
#pragma unroll
    for (int j = 0; j < 4; ++j) acc[i][j] = (f32x4){0.f, 0.f, 0.f, 0.f};

  const bf16_t* A = xbf + (size_t)m0 * CC;
  const bf16_t* B = wt + (size_t)z * CC * CC + (size_t)n0 * CC;
  gemm_core(A, CC, B, CC, CC / 32, As, Bs, acc);

  int l = threadIdx.x & 63, w = threadIdx.x >> 6;
  int wr = (w >> 1) * 64, wc = (w & 1) * 64;
  const float* bias = (z == 0) ? bq : (z == 1) ? bk : bv;
  float scale = (z == 0) ? rsqrtf((float)CC) : 1.0f;

#pragma unroll
  for (int mi = 0; mi < 4; ++mi) {
#pragma unroll
    for (int ni = 0; ni < 4; ++ni) {
      int col = n0 + wc + ni * 16 + (l & 15);
      int rbase = m0 + wr + mi * 16 + (l >> 4) * 4;
      float bcol = bias[col];
#pragma unroll
      for (int r = 0; r < 4; ++r) {
        int m = rbase + r;
        float v = (acc[mi][ni][r] + bcol) * scale;
        bf16_t h = (bf16_t)v;
        if (z == 0) {
          qb[(size_t)m * CC + col] = h;
        } else if (z == 1) {
          kb[(size_t)m * CC + col] = h;
        } else {
          int b = m >> 11, tt = m & (TT - 1);
          vt[((size_t)b * CC + col) * TT + tt] = h;  // v^T: [B][H][T]
        }
      }
    }
  }
}

// ---------------------------------------------------------------------------
// Kernel 4: S = q k^T (scale folded into q), causal mask + (==0 -> -inf),
// stored fp16.  Only lower-triangular 128x128 blocks computed.
// ---------------------------------------------------------------------------
__global__ __launch_bounds__(256) void s_gemm_kernel(
    const bf16_t* __restrict__ qb, const bf16_t* __restrict__ kb,
    _Float16* __restrict__ S) {
  int tj = blockIdx.x, ti = blockIdx.y, b = blockIdx.z;
  if (tj > ti) return;
  __shared__ bf16_t As[4][4096], Bs[4][4096];
  int m0 = ti * 128, n0 = tj * 128;

  f32x4 acc[4][4];
#pragma unroll
  for (int i = 0; i < 4; ++i)
#pragma unroll
    for (int j = 0; j < 4; ++j) acc[i][j] = (f32x4){0.f, 0.f, 0.f, 0.f};

  const bf16_t* A = qb + ((size_t)b * TT + m0) * CC;
  const bf16_t* B = kb + ((size_t)b * TT + n0) * CC;
  gemm_core(A, CC, B, CC, CC / 32, As, Bs, acc);

  _Float16* Sb = S + (size_t)b * TT * TT;
  int l = threadIdx.x & 63, w = threadIdx.x >> 6;
  int wr = (w >> 1) * 64, wc = (w & 1) * 64;
#pragma unroll
  for (int mi = 0; mi < 4; ++mi) {
#pragma unroll
    for (int ni = 0; ni < 4; ++ni) {
      int j = n0 + wc + ni * 16 + (l & 15);
      int ibase = m0 + wr + mi * 16 + (l >> 4) * 4;
#pragma unroll
      for (int r = 0; r < 4; ++r) {
        int i = ibase + r;
        float v = acc[mi][ni][r];
        if (j > i || v == 0.0f) v = -INFINITY;  // causal + reference quirk
        Sb[(size_t)i * TT + j] = (_Float16)v;
      }
    }
  }
}

// ---------------------------------------------------------------------------
// Kernel 5: rowstat+normalize — per-row max M, L = sum exp(s-M); writes
// P = exp(s-M)/L as bf16, rows zero-padded to the next 128 boundary.
// One half8 load / bf16x8 store per thread (pe <= 2048 = 256*8).
// ---------------------------------------------------------------------------
__global__ __launch_bounds__(256) void rowstat_kernel(
    const _Float16* __restrict__ S, bf16_t* __restrict__ P) {
  int row = blockIdx.x & (TT - 1);
  int b = blockIdx.x >> 11;
  const _Float16* s = S + ((size_t)b * TT + row) * TT;
  bf16_t* p = P + ((size_t)b * TT + row) * TT;
  int pe = ((row >> 7) + 1) << 7;  // padded causal length, multiple of 128
  int j = threadIdx.x * 8;
  bool live = j < pe;

  float f[8];
  if (live) {
    half8 h = *(const half8*)(s + j);
#pragma unroll
    for (int k = 0; k < 8; ++k) f[k] = (float)h[k];
  } else {
#pragma unroll
    for (int k = 0; k < 8; ++k) f[k] = -INFINITY;
  }

  float m = f[0];
#pragma unroll
  for (int k = 1; k < 8; ++k) m = fmaxf(m, f[k]);
#pragma unroll
  for (int off = 32; off > 0; off >>= 1) m = fmaxf(m, __shfl_xor(m, off));
  __shared__ float redm[4];
  int w = threadIdx.x >> 6, l = threadIdx.x & 63;
  if (l == 0) redm[w] = m;
  __syncthreads();
  m = fmaxf(fmaxf(redm[0], redm[1]), fmaxf(redm[2], redm[3]));

  float e[8];
  float sum = 0.f;
#pragma unroll
  for (int k = 0; k < 8; ++k) {
    e[k] = __expf(f[k] - m);  // exp(-inf)=0 for masked slots
    sum += e[k];
  }
#pragma unroll
  for (int off = 32; off > 0; off >>= 1) sum += __shfl_xor(sum, off);
  __shared__ float reds[4];
  if (l == 0) reds[w] = sum;
  __syncthreads();
  float inv = 1.0f / (reds[0] + reds[1] + reds[2] + reds[3]);

  if (live) {
    bf16x8 o;
#pragma unroll
    for (int k = 0; k < 8; ++k) o[k] = (bf16_t)(e[k] * inv);
    *(bf16x8*)(p + j) = o;
  }
}

// ---------------------------------------------------------------------------
// Kernel 6: O = P @ V   (A = P row-major [T][T], Bt = v^T [B][H][T]).
// K-loop truncated at the causal boundary.  Heaviest m-tiles first.
// ---------------------------------------------------------------------------
__global__ __launch_bounds__(256) void o_gemm_kernel(
    const bf16_t* __restrict__ P, const bf16_t* __restrict__ vt,
    float* __restrict__ out) {
  int nj = blockIdx.x;
  int ti = (int)gridDim.y - 1 - (int)blockIdx.y;  // heavy first
  int b = blockIdx.z;
  __shared__ bf16_t As[4][4096], Bs[4][4096];
  int m0 = ti * 128, n0 = nj * 128;

  f32x4 acc[4][4];
#pragma unroll
  for (int i = 0; i < 4; ++i)
#pragma unroll
    for (int j = 0; j < 4; ++j) acc[i][j] = (f32x4){0.f, 0.f, 0.f, 0.f};

  const bf16_t* A = P + ((size_t)b * TT + m0) * TT;
  const bf16_t* B = vt + ((size_t)b * CC + n0) * TT;
  gemm_core(A, TT, B, TT, (ti + 1) * 4, As, Bs, acc);

  float* Ob = out + (size_t)b * TT * CC;
  int l = threadIdx.x & 63, w = threadIdx.x >> 6;
  int wr = (w >> 1) * 64, wc = (w & 1) * 64;
#pragma unroll
  for (int mi = 0; mi < 4; ++mi) {
#pragma unroll
    for (int ni = 0; ni < 4; ++ni) {
      int col = n0 + wc + ni * 16 + (l & 15);
      int ibase = m0 + wr + mi * 16 + (l >> 4) * 4;
#pragma unroll
      for (int r = 0; r < 4; ++r)
        Ob[(size_t)(ibase + r) * CC + col] = acc[mi][ni][r];
    }
  }
}

// ---------------------------------------------------------------------------
extern "C" void kernel_launch(void* const* d_in, const int* in_sizes, int n_in,
                              void* d_out, int out_size, void* d_ws,
                              size_t ws_size, hipStream_t stream) {
  const float* x = (const float*)d_in[0];
  const float* Wq = (const float*)d_in[1];
  const float* bq = (const float*)d_in[2];
  const float* Wk = (const float*)d_in[3];
  const float* bk = (const float*)d_in[4];
  const float* Wv = (const float*)d_in[5];
  const float* bv = (const float*)d_in[6];
  float* out = (float*)d_out;

  char* ws = (char*)d_ws;
  size_t off = 0;
  auto carve = [&](size_t bytes) -> char* {
    char* p = ws + off;
    off += (bytes + 255) & ~(size_t)255;
    return p;
  };
  const size_t M = (size_t)BB * TT;  // 8192
  bf16_t* xbf = (bf16_t*)carve(M * CC * 2);            // 12.6 MB
  bf16_t* wt  = (bf16_t*)carve(3ull * CC * CC * 2);    // 3.5 MB
  bf16_t* qb  = (bf16_t*)carve(M * CC * 2);            // 12.6 MB
  bf16_t* kb  = (bf16_t*)carve(M * CC * 2);            // 12.6 MB
  bf16_t* vt  = (bf16_t*)carve(M * CC * 2);            // 12.6 MB (as [B][H][T])
  _Float16* S = (_Float16*)carve((size_t)BB * TT * TT * 2);  // 33.5 MB
  bf16_t* P   = (bf16_t*)carve((size_t)BB * TT * TT * 2);    // 33.5 MB
  (void)off; (void)ws_size;

  // 1+2: input prep
  cast_x_kernel<<<(M * CC / 8 + 255) / 256, 256, 0, stream>>>(x, xbf);
  transpose_w_kernel<<<dim3(CC / 32, CC / 32, 3), dim3(32, 8, 1), 0, stream>>>(
      Wq, Wk, Wv, wt);
  // 3: q,k,v
  qkv_gemm_kernel<<<dim3(CC / 128, M / 128, 3), 256, 0, stream>>>(
      xbf, wt, bq, bk, bv, qb, kb, vt);
  // 4: S = q k^T (lower-tri blocks, fp16)
  s_gemm_kernel<<<dim3(TT / 128, TT / 128, BB), 256, 0, stream>>>(qb, kb, S);
  // 5: softmax rows -> P (bf16, zero-padded)
  rowstat_kernel<<<BB * TT, 256, 0, stream>>>(S, P);
  // 6: O = P V
  o_gemm_kernel<<<dim3(CC / 128, TT / 128, BB), 256, 0, stream>>>(P, vt, out);
}

// Round 3
// 248.374 us; speedup vs baseline: 1.0073x; 1.0073x over previous
//
#include <hip/hip_runtime.h>
#include <math.h>

// ---------------------------------------------------------------------------
// AttentionLayer: out = softmax(mask(q k^T * scale)) @ v,  q/k/v = x@W + b
// B=4, T=2048, C=H=768.  bf16 MFMA (16x16x32), fp32 accumulate.
// R6 (this round), from R5 post-mortem (250 us, qkv 75 us, MfmaUtil 14%,
//     Occupancy 15.7%, FETCH 98 MB):
//   - gemm_core: 4-slot/64KB (2 blocks/CU) -> 3-slot/48KB (3 blocks/CU),
//     depth-2 prefetch, steady s_waitcnt vmcnt(4) across one raw s_barrier
//     per k-tile.  sched_barrier(0) both BEFORE the wait (stops rule-#18
//     MFMA sink past the barrier -> LDS overwrite race) and after it.
//   - T1 XCD-chunked swizzle on all three GEMM grids so blocks sharing an
//     A-tile co-locate on one XCD's L2 (qkv A was fetched ~6x across XCDs).
//   - s_gemm: live-only 1D grid (544 lower-tri blocks, triangular decode);
//     o_gemm: balance-paired heavy/light ti permutation per XCD chunk.
// ---------------------------------------------------------------------------

#define BB 4
#define TT 2048
#define CC 768

typedef __bf16 bf16_t;
typedef __bf16 bf16x8 __attribute__((ext_vector_type(8)));
typedef _Float16 half8 __attribute__((ext_vector_type(8)));
typedef float f32x4 __attribute__((ext_vector_type(4)));

// ---------------------------------------------------------------------------
// async global->LDS 16B copy (wave-uniform LDS base + lane*16 implicit)
// ---------------------------------------------------------------------------
__device__ __forceinline__ void async_load16(void* lds, const void* g) {
  __builtin_amdgcn_global_load_lds(
      (const __attribute__((address_space(1))) void*)g,
      (__attribute__((address_space(3))) void*)lds, 16, 0, 0);
}

// Stage a 128x32 bf16 tile (row-major, row stride ld elements) into LDS.
// LDS layout: row-major 128x32, 8-elem chunks XOR-swizzled within a row:
// physical chunk p of row r holds logical chunk q = p ^ (r & 3).
// 2 global_load_lds per thread per tile (4 per k-tile incl. A and B).
__device__ __forceinline__ void stage_tile(const bf16_t* __restrict__ g0,
                                           int ld, bf16_t* lds, int t) {
  int w = t >> 6, l = t & 63;
#pragma unroll
  for (int i = 0; i < 2; ++i) {
    int c = i * 256 + w * 64 + l;   // linear 16B-chunk id in LDS
    int row = c >> 2;
    int p = c & 3;
    int q = p ^ (row & 3);          // logical chunk to fetch
    async_load16(lds + i * 2048 + w * 512,  // wave-uniform base (elements)
                 g0 + row * ld + q * 8);
  }
}

// Read one MFMA fragment (8 bf16, 16B) for logical (row r, k-chunk q).
__device__ __forceinline__ bf16x8 read_frag(const bf16_t* lds, int r, int q) {
  int p = q ^ (r & 3);
  return *(const bf16x8*)(lds + r * 32 + p * 8);
}

// One 128x128x32 MFMA step from a published LDS buffer pair.
__device__ __forceinline__ void mfma_tile(const bf16_t* Ab, const bf16_t* Bb,
                                          int wr, int wc, int l,
                                          f32x4 acc[4][4]) {
  bf16x8 af[4], bfr[4];
  int q = l >> 4;
#pragma unroll
  for (int i = 0; i < 4; ++i) {
    af[i] = read_frag(Ab, wr + i * 16 + (l & 15), q);
    bfr[i] = read_frag(Bb, wc + i * 16 + (l & 15), q);
  }
#pragma unroll
  for (int mi = 0; mi < 4; ++mi)
#pragma unroll
    for (int ni = 0; ni < 4; ++ni)
      acc[mi][ni] = __builtin_amdgcn_mfma_f32_16x16x32_bf16(
          af[mi], bfr[ni], acc[mi][ni], 0, 0, 0);
}

// ---------------------------------------------------------------------------
// Core: C[128x128] += A[128xK] * B^T.  Any kTiles >= 4.
//
// 3-slot circular pipeline (48 KB LDS -> 3 blocks/CU), depth-2 prefetch,
// counted vmcnt:
//   body(kt):  sched_barrier(0)          // pin body kt-1 (incl. its MFMAs
//                                        // and ds_read drains) above
//              s_waitcnt vmcnt(4)        // kt's 4 loads done; kt+1's fly on
//              s_barrier                 // all waves staged kt, read kt-1
//              sched_barrier(0)
//              stage(kt+2) -> slot (kt+2)%3   [iff kt+2 < kTiles]
//              mfma(slot kt%3)
// Hazards: stage slot (kt+2)%3 == slot of kt-1, whose ds_reads are drained
// by every wave before it reaches this body's barrier (fenced above).
// mfma reads slot kt%3, staged 2 bodies ago, completed by vmcnt(4)+barrier.
// kt stays a multiple of 3 in the main loop -> all slot indices static.
// ---------------------------------------------------------------------------
__device__ __forceinline__ void gemm_core(const bf16_t* __restrict__ A, int lda,
                                          const bf16_t* __restrict__ B, int ldb,
                                          int kTiles, bf16_t (*As)[4096],
                                          bf16_t (*Bs)[4096],
                                          f32x4 acc[4][4]) {
  int t = threadIdx.x;
  int l = t & 63;
  int w = t >> 6;
  int wr = (w >> 1) * 64;  // wave row offset in 128-tile
  int wc = (w & 1) * 64;   // wave col offset

  // prologue: stage tiles 0,1 -> slots 0,1 (8 loads/thread in flight)
  stage_tile(A, lda, As[0], t);
  stage_tile(B, ldb, Bs[0], t);
  stage_tile(A + 32, lda, As[1], t);
  stage_tile(B + 32, ldb, Bs[1], t);

#define GEMM_BODY(J, WAITN)                                            \
  {                                                                    \
    __builtin_amdgcn_sched_barrier(0);                                 \
    asm volatile("s_waitcnt vmcnt(" #WAITN ")" ::: "memory");          \
    __builtin_amdgcn_s_barrier();                                      \
    __builtin_amdgcn_sched_barrier(0);                                 \
    if (kt + (J) + 2 < kTiles) {                                       \
      stage_tile(A + (kt + (J) + 2) * 32, lda, As[((J) + 2) % 3], t);  \
      stage_tile(B + (kt + (J) + 2) * 32, ldb, Bs[((J) + 2) % 3], t);  \
    }                                                                  \
    mfma_tile(As[(J)], Bs[(J)], wr, wc, l, acc);                       \
  }

  int kt = 0;
  for (; kt + 3 < kTiles; kt += 3) {
    GEMM_BODY(0, 4)
    GEMM_BODY(1, 4)
    GEMM_BODY(2, 4)
  }
  int rem = kTiles - kt;  // 1, 2, or 3
  if (rem == 3) {
    GEMM_BODY(0, 4)
    GEMM_BODY(1, 4)
    GEMM_BODY(2, 0)
  } else if (rem == 2) {
    GEMM_BODY(0, 4)
    GEMM_BODY(1, 0)
  } else {
    GEMM_BODY(0, 0)
  }
#undef GEMM_BODY
}

// C/D layout (m89-verified): col = lane&15, row = (lane>>4)*4 + reg.

// ---------------------------------------------------------------------------
// Kernel 1: cast x (fp32) -> bf16, 8 elems/thread
// ---------------------------------------------------------------------------
__global__ __launch_bounds__(256) void cast_x_kernel(
    const float* __restrict__ x, bf16_t* __restrict__ xbf) {
  int i = blockIdx.x * 256 + threadIdx.x;
  const float4* xin = (const float4*)x;
  float4 a = xin[i * 2];
  float4 b = xin[i * 2 + 1];
  bf16_t tmp[8];
  tmp[0] = (bf16_t)a.x; tmp[1] = (bf16_t)a.y;
  tmp[2] = (bf16_t)a.z; tmp[3] = (bf16_t)a.w;
  tmp[4] = (bf16_t)b.x; tmp[5] = (bf16_t)b.y;
  tmp[6] = (bf16_t)b.z; tmp[7] = (bf16_t)b.w;
  *(uint4*)(xbf + (size_t)i * 8) = *(const uint4*)tmp;
}

// ---------------------------------------------------------------------------
// Kernel 2: transpose+cast the three weight matrices [C][H] -> bf16 [H][C]
// ---------------------------------------------------------------------------
__global__ __launch_bounds__(256) void transpose_w_kernel(
    const float* __restrict__ Wq, const float* __restrict__ Wk,
    const float* __restrict__ Wv, bf16_t* __restrict__ wt) {
  int z = blockIdx.z;
  const float* W = (z == 0) ? Wq : (z == 1) ? Wk : Wv;
  bf16_t* out = wt + (size_t)z * CC * CC;
  __shared__ float tile[32][33];
  int tx = threadIdx.x;  // 0..31
  int ty = threadIdx.y;  // 0..7
  int n0 = blockIdx.x * 32;
  int c0 = blockIdx.y * 32;
#pragma unroll
  for (int k = 0; k < 4; ++k)
    tile[ty + k * 8][tx] = W[(size_t)(c0 + ty + k * 8) * CC + n0 + tx];
  __syncthreads();
#pragma unroll
  for (int k = 0; k < 4; ++k)
    out[(size_t)(n0 + ty + k * 8) * CC + c0 + tx] =
        (bf16_t)tile[tx][ty + k * 8];
}

// ---------------------------------------------------------------------------
// Kernel 3: QKV GEMM, 1D grid of 1152 = 8 XCD chunks x 144.
// Chunk-local order: n fastest within an m-row -> the 6 blocks sharing an
// A m-tile run consecutively on ONE XCD (L2 catches the re-reads).
// z=0: q (scaled by H^-1/2), z=1: k, z=2: v transposed.
// ---------------------------------------------------------------------------
__global__ __launch_bounds__(256) void qkv_gemm_kernel(
    const bf16_t* __restrict__ xbf, const bf16_t* __restrict__ wt,
    const float* __restrict__ bq, const float* __restrict__ bk,
    const float* __restrict__ bv, bf16_t* __restrict__ qb,
    bf16_t* __restrict__ kb, bf16_t* __restrict__ vt) {
  __shared__ bf16_t As[3][4096], Bs[3][4096];
  int bid = blockIdx.x;
  int work = (bid & 7) * 144 + (bid >> 3);  // 1152 = 8 * 144 (bijective)
  int z = work / 384;
  int rw = work - z * 384;
  int m0 = (rw / 6) * 128;
  int n0 = (rw % 6) * 128;

  f32x4 acc[4][4];
#pragma unroll
  for (int i = 0; i < 4; ++i)
#pragma unroll
    for (int j = 0; j < 4; ++j) acc[i][j] = (f32x4){0.f, 0.f, 0.f, 0.f};

  const bf16_t* A = xbf + (size_t)m0 * CC;
  const bf16_t* B = wt + (size_t)z * CC * CC + (size_t)n0 * CC;
  gemm_core(A, CC, B, CC, CC / 32, As, Bs, acc);

  int l = threadIdx.x & 63, w = threadIdx.x >> 6;
  int wr = (w >> 1) * 64, wc = (w & 1) * 64;
  const float* bias = (z == 0) ? bq : (z == 1) ? bk : bv;
  float scale = (z == 0) ? rsqrtf((float)CC) : 1.0f;

#pragma unroll
  for (int mi = 0; mi < 4; ++mi) {
#pragma unroll
    for (int ni = 0; ni < 4; ++ni) {
      int col = n0 + wc + ni * 16 + (l & 15);
      int rbase = m0 + wr + mi * 16 + (l >> 4) * 4;
      float bcol = bias[col];
#pragma unroll
      for (int r = 0; r < 4; ++r) {
        int m = rbase + r;
        float v = (acc[mi][ni][r] + bcol) * scale;
        bf16_t h = (bf16_t)v;
        if (z == 0) {
          qb[(size_t)m * CC + col] = h;
        } else if (z == 1) {
          kb[(size_t)m * CC + col] = h;
        } else {
          int b = m >> 11, tt = m & (TT - 1);
          vt[((size_t)b * CC + col) * TT + tt] = h;  // v^T: [B][H][T]
        }
      }
    }
  }
}

// ---------------------------------------------------------------------------
// Kernel 4: S = q k^T (scale folded into q), causal mask + (==0 -> -inf),
// stored fp16.  1D grid of 544 LIVE lower-tri blocks = 8 XCD chunks x 68;
// triangular decode (guarded sqrt).  Same-ti blocks consecutive -> q-tile
// L2 reuse; all 16 k-tiles (3.1 MB) fit one XCD L2.
// ---------------------------------------------------------------------------
__global__ __launch_bounds__(256) void s_gemm_kernel(
    const bf16_t* __restrict__ qb, const bf16_t* __restrict__ kb,
    _Float16* __restrict__ S) {
  __shared__ bf16_t As[3][4096], Bs[3][4096];
  int bid = blockIdx.x;
  int work = (bid & 7) * 68 + (bid >> 3);  // 544 = 8 * 68 (bijective)
  int b = work / 136;
  int t = work - b * 136;
  int ti = (int)((sqrtf(8.f * (float)t + 1.f) - 1.f) * 0.5f);
  while ((ti + 1) * (ti + 2) / 2 <= t) ++ti;  // guard fp rounding
  while (ti * (ti + 1) / 2 > t) --ti;
  int tj = t - ti * (ti + 1) / 2;
  int m0 = ti * 128, n0 = tj * 128;

  f32x4 acc[4][4];
#pragma unroll
  for (int i = 0; i < 4; ++i)
#pragma unroll
    for (int j = 0; j < 4; ++j) acc[i][j] = (f32x4){0.f, 0.f, 0.f, 0.f};

  const bf16_t* A = qb + ((size_t)b * TT + m0) * CC;
  const bf16_t* B = kb + ((size_t)b * TT + n0) * CC;
  gemm_core(A, CC, B, CC, CC / 32, As, Bs, acc);

  _Float16* Sb = S + (size_t)b * TT * TT;
  int l = threadIdx.x & 63, w = threadIdx.x >> 6;
  int wr = (w >> 1) * 64, wc = (w & 1) * 64;
#pragma unroll
  for (int mi = 0; mi < 4; ++mi) {
#pragma unroll
    for (int ni = 0; ni < 4; ++ni) {
      int j = n0 + wc + ni * 16 + (l & 15);
      int ibase = m0 + wr + mi * 16 + (l >> 4) * 4;
#pragma unroll
      for (int r = 0; r < 4; ++r) {
        int i = ibase + r;
        float v = acc[mi][ni][r];
        if (j > i || v == 0.0f) v = -INFINITY;  // causal + reference quirk
        Sb[(size_t)i * TT + j] = (_Float16)v;
      }
    }
  }
}

// ---------------------------------------------------------------------------
// Kernel 5: rowstat+normalize — per-row max M, L = sum exp(s-M); writes
// P = exp(s-M)/L as bf16, rows zero-padded to the next 128 boundary.
// One half8 load / bf16x8 store per thread (pe <= 2048 = 256*8).
// ---------------------------------------------------------------------------
__global__ __launch_bounds__(256) void rowstat_kernel(
    const _Float16* __restrict__ S, bf16_t* __restrict__ P) {
  int row = blockIdx.x & (TT - 1);
  int b = blockIdx.x >> 11;
  const _Float16* s = S + ((size_t)b * TT + row) * TT;
  bf16_t* p = P + ((size_t)b * TT + row) * TT;
  int pe = ((row >> 7) + 1) << 7;  // padded causal length, multiple of 128
  int j = threadIdx.x * 8;
  bool live = j < pe;

  float f[8];
  if (live) {
    half8 h = *(const half8*)(s + j);
#pragma unroll
    for (int k = 0; k < 8; ++k) f[k] = (float)h[k];
  } else {
#pragma unroll
    for (int k = 0; k < 8; ++k) f[k] = -INFINITY;
  }

  float m = f[0];
#pragma unroll
  for (int k = 1; k < 8; ++k) m = fmaxf(m, f[k]);
#pragma unroll
  for (int off = 32; off > 0; off >>= 1) m = fmaxf(m, __shfl_xor(m, off));
  __shared__ float redm[4];
  int w = threadIdx.x >> 6, l = threadIdx.x & 63;
  if (l == 0) redm[w] = m;
  __syncthreads();
  m = fmaxf(fmaxf(redm[0], redm[1]), fmaxf(redm[2], redm[3]));

  float e[8];
  float sum = 0.f;
#pragma unroll
  for (int k = 0; k < 8; ++k) {
    e[k] = __expf(f[k] - m);  // exp(-inf)=0 for masked slots
    sum += e[k];
  }
#pragma unroll
  for (int off = 32; off > 0; off >>= 1) sum += __shfl_xor(sum, off);
  __shared__ float reds[4];
  if (l == 0) reds[w] = sum;
  __syncthreads();
  float inv = 1.0f / (reds[0] + reds[1] + reds[2] + reds[3]);

  if (live) {
    bf16x8 o;
#pragma unroll
    for (int k = 0; k < 8; ++k) o[k] = (bf16_t)(e[k] * inv);
    *(bf16x8*)(p + j) = o;
  }
}

// ---------------------------------------------------------------------------
// Kernel 6: O = P @ V   (A = P row-major [T][T], Bt = v^T [B][H][T]).
// 1D grid of 384 = 8 XCD chunks x 48.  Within a chunk: nj fastest (A-tile
// reuse), ti from the balance-paired permutation {15,0,14,1,...} so every
// 8-ti chunk sums to equal causal K work; heavy tiles lead each chunk.
// K-loop truncated at the causal boundary.
// ---------------------------------------------------------------------------
__global__ __launch_bounds__(256) void o_gemm_kernel(
    const bf16_t* __restrict__ P, const bf16_t* __restrict__ vt,
    float* __restrict__ out) {
  __shared__ bf16_t As[3][4096], Bs[3][4096];
  int bid = blockIdx.x;
  int work = (bid & 7) * 48 + (bid >> 3);  // 384 = 8 * 48 (bijective)
  int b = work / 96;
  int rw = work - b * 96;
  int i = rw / 6, nj = rw % 6;
  int ti = (i & 1) ? ((i - 1) >> 1) : (15 - (i >> 1));  // 15,0,14,1,...,8,7
  int m0 = ti * 128, n0 = nj * 128;

  f32x4 acc[4][4];
#pragma unroll
  for (int ii = 0; ii < 4; ++ii)
#pragma unroll
    for (int j = 0; j < 4; ++j) acc[ii][j] = (f32x4){0.f, 0.f, 0.f, 0.f};

  const bf16_t* A = P + ((size_t)b * TT + m0) * TT;
  const bf16_t* B = vt + ((size_t)b * CC + n0) * TT;
  gemm_core(A, TT, B, TT, (ti + 1) * 4, As, Bs, acc);

  float* Ob = out + (size_t)b * TT * CC;
  int l = threadIdx.x & 63, w = threadIdx.x >> 6;
  int wr = (w >> 1) * 64, wc = (w & 1) * 64;
#pragma unroll
  for (int mi = 0; mi < 4; ++mi) {
#pragma unroll
    for (int ni = 0; ni < 4; ++ni) {
      int col = n0 + wc + ni * 16 + (l & 15);
      int ibase = m0 + wr + mi * 16 + (l >> 4) * 4;
#pragma unroll
      for (int r = 0; r < 4; ++r)
        Ob[(size_t)(ibase + r) * CC + col] = acc[mi][ni][r];
    }
  }
}

// ---------------------------------------------------------------------------
extern "C" void kernel_launch(void* const* d_in, const int* in_sizes, int n_in,
                              void* d_out, int out_size, void* d_ws,
                              size_t ws_size, hipStream_t stream) {
  const float* x = (const float*)d_in[0];
  const float* Wq = (const float*)d_in[1];
  const float* bq = (const float*)d_in[2];
  const float* Wk = (const float*)d_in[3];
  const float* bk = (const float*)d_in[4];
  const float* Wv = (const float*)d_in[5];
  const float* bv = (const float*)d_in[6];
  float* out = (float*)d_out;

  char* ws = (char*)d_ws;
  size_t off = 0;
  auto carve = [&](size_t bytes) -> char* {
    char* p = ws + off;
    off += (bytes + 255) & ~(size_t)255;
    return p;
  };
  const size_t M = (size_t)BB * TT;  // 8192
  bf16_t* xbf = (bf16_t*)carve(M * CC * 2);            // 12.6 MB
  bf16_t* wt  = (bf16_t*)carve(3ull * CC * CC * 2);    // 3.5 MB
  bf16_t* qb  = (bf16_t*)carve(M * CC * 2);            // 12.6 MB
  bf16_t* kb  = (bf16_t*)carve(M * CC * 2);            // 12.6 MB
  bf16_t* vt  = (bf16_t*)carve(M * CC * 2);            // 12.6 MB (as [B][H][T])
  _Float16* S = (_Float16*)carve((size_t)BB * TT * TT * 2);  // 33.5 MB
  bf16_t* P   = (bf16_t*)carve((size_t)BB * TT * TT * 2);    // 33.5 MB
  (void)off; (void)ws_size;

  // 1+2: input prep
  cast_x_kernel<<<(M * CC / 8 + 255) / 256, 256, 0, stream>>>(x, xbf);
  transpose_w_kernel<<<dim3(CC / 32, CC / 32, 3), dim3(32, 8, 1), 0, stream>>>(
      Wq, Wk, Wv, wt);
  // 3: q,k,v
  qkv_gemm_kernel<<<1152, 256, 0, stream>>>(xbf, wt, bq, bk, bv, qb, kb, vt);
  // 4: S = q k^T (lower-tri blocks, fp16)
  s_gemm_kernel<<<544, 256, 0, stream>>>(qb, kb, S);
  // 5: softmax rows -> P (bf16, zero-padded)
  rowstat_kernel<<<BB * TT, 256, 0, stream>>>(S, P);
  // 6: O = P V
  o_gemm_kernel<<<384, 256, 0, stream>>>(P, vt, out);
}

// Round 4
// 224.167 us; speedup vs baseline: 1.1160x; 1.1080x over previous
//
#include <hip/hip_runtime.h>
#include <math.h>

// ---------------------------------------------------------------------------
// AttentionLayer: out = softmax(mask(q k^T * scale)) @ v,  q/k/v = x@W + b
// B=4, T=2048, C=H=768.  bf16 MFMA (16x16x32), fp32 accumulate.
// R7 (this round), from R6 post-mortem (248 us; qkv 87 us, MfmaUtil 12.6%,
//     FETCH fixed 98->33 MB but dur WORSE => latency-bound, and every added
//     scheduling pin lowered MfmaUtil = the m141 compiler-defeat failure):
//   - gemm_core REVERTED to the proven R3 static double-buffer: plain
//     __syncthreads, 32 KB LDS (5 blocks/CU static cap -> TLP is what hides
//     latency at this shape, not source-level pipelining).
//   - KEPT: XCD-chunked 1D grids (qkv FETCH -3x), live-only triangular
//     s_gemm grid, balance-paired o_gemm permutation.
//   - rowstat -> wave-per-row (4 rows/block, no LDS, no barriers).
// ---------------------------------------------------------------------------

#define BB 4
#define TT 2048
#define CC 768

typedef __bf16 bf16_t;
typedef __bf16 bf16x8 __attribute__((ext_vector_type(8)));
typedef _Float16 half8 __attribute__((ext_vector_type(8)));
typedef float f32x4 __attribute__((ext_vector_type(4)));

// ---------------------------------------------------------------------------
// async global->LDS 16B copy (wave-uniform LDS base + lane*16 implicit)
// ---------------------------------------------------------------------------
__device__ __forceinline__ void async_load16(void* lds, const void* g) {
  __builtin_amdgcn_global_load_lds(
      (const __attribute__((address_space(1))) void*)g,
      (__attribute__((address_space(3))) void*)lds, 16, 0, 0);
}

// Stage a 128x32 bf16 tile (row-major, row stride ld elements) into LDS.
// LDS layout: row-major 128x32, 8-elem chunks XOR-swizzled within a row:
// physical chunk p of row r holds logical chunk q = p ^ (r & 3).
__device__ __forceinline__ void stage_tile(const bf16_t* __restrict__ g0,
                                           int ld, bf16_t* lds, int t) {
  int w = t >> 6, l = t & 63;
#pragma unroll
  for (int i = 0; i < 2; ++i) {
    int c = i * 256 + w * 64 + l;   // linear 16B-chunk id in LDS
    int row = c >> 2;
    int p = c & 3;
    int q = p ^ (row & 3);          // logical chunk to fetch
    async_load16(lds + i * 2048 + w * 512,  // wave-uniform base (elements)
                 g0 + row * ld + q * 8);
  }
}

// Read one MFMA fragment (8 bf16, 16B) for logical (row r, k-chunk q).
__device__ __forceinline__ bf16x8 read_frag(const bf16_t* lds, int r, int q) {
  int p = q ^ (r & 3);
  return *(const bf16x8*)(lds + r * 32 + p * 8);
}

// One 128x128x32 MFMA step from a published LDS buffer pair.
__device__ __forceinline__ void mfma_tile(const bf16_t* Ab, const bf16_t* Bb,
                                          int wr, int wc, int l,
                                          f32x4 acc[4][4]) {
  bf16x8 af[4], bfr[4];
  int q = l >> 4;
#pragma unroll
  for (int i = 0; i < 4; ++i) {
    af[i] = read_frag(Ab, wr + i * 16 + (l & 15), q);
    bfr[i] = read_frag(Bb, wc + i * 16 + (l & 15), q);
  }
#pragma unroll
  for (int mi = 0; mi < 4; ++mi)
#pragma unroll
    for (int ni = 0; ni < 4; ++ni)
      acc[mi][ni] = __builtin_amdgcn_mfma_f32_16x16x32_bf16(
          af[mi], bfr[ni], acc[mi][ni], 0, 0, 0);
}

// Core: C[128x128] += A[128xK] * B^T.  kTiles must be EVEN.
// R3-proven unroll-2 static double-buffer: one barrier per k-tile; each async
// stage has a full MFMA phase in flight before the barrier that drains it.
// Plain __syncthreads (compiler manages waitcnt); 32 KB LDS -> 5 blocks/CU.
__device__ __forceinline__ void gemm_core(const bf16_t* __restrict__ A, int lda,
                                          const bf16_t* __restrict__ B, int ldb,
                                          int kTiles, bf16_t* As0, bf16_t* As1,
                                          bf16_t* Bs0, bf16_t* Bs1,
                                          f32x4 acc[4][4]) {
  int t = threadIdx.x;
  int l = t & 63;
  int w = t >> 6;
  int wr = (w >> 1) * 64;  // wave row offset in 128-tile
  int wc = (w & 1) * 64;   // wave col offset

  stage_tile(A, lda, As0, t);  // k-tile 0 -> buf0
  stage_tile(B, ldb, Bs0, t);

  for (int kt = 0; kt < kTiles; kt += 2) {
    __syncthreads();  // publish buf0(kt); prior buf1 reads complete
    stage_tile(A + (kt + 1) * 32, lda, As1, t);   // prefetch kt+1
    stage_tile(B + (kt + 1) * 32, ldb, Bs1, t);
    mfma_tile(As0, Bs0, wr, wc, l, acc);
    __syncthreads();  // publish buf1(kt+1); buf0 reads complete
    if (kt + 2 < kTiles) {
      stage_tile(A + (kt + 2) * 32, lda, As0, t);  // prefetch kt+2
      stage_tile(B + (kt + 2) * 32, ldb, Bs0, t);
    }
    mfma_tile(As1, Bs1, wr, wc, l, acc);
  }
}

// C/D layout (m89-verified): col = lane&15, row = (lane>>4)*4 + reg.

// ---------------------------------------------------------------------------
// Kernel 1: cast x (fp32) -> bf16, 8 elems/thread
// ---------------------------------------------------------------------------
__global__ __launch_bounds__(256) void cast_x_kernel(
    const float* __restrict__ x, bf16_t* __restrict__ xbf) {
  int i = blockIdx.x * 256 + threadIdx.x;
  const float4* xin = (const float4*)x;
  float4 a = xin[i * 2];
  float4 b = xin[i * 2 + 1];
  bf16_t tmp[8];
  tmp[0] = (bf16_t)a.x; tmp[1] = (bf16_t)a.y;
  tmp[2] = (bf16_t)a.z; tmp[3] = (bf16_t)a.w;
  tmp[4] = (bf16_t)b.x; tmp[5] = (bf16_t)b.y;
  tmp[6] = (bf16_t)b.z; tmp[7] = (bf16_t)b.w;
  *(uint4*)(xbf + (size_t)i * 8) = *(const uint4*)tmp;
}

// ---------------------------------------------------------------------------
// Kernel 2: transpose+cast the three weight matrices [C][H] -> bf16 [H][C]
// ---------------------------------------------------------------------------
__global__ __launch_bounds__(256) void transpose_w_kernel(
    const float* __restrict__ Wq, const float* __restrict__ Wk,
    const float* __restrict__ Wv, bf16_t* __restrict__ wt) {
  int z = blockIdx.z;
  const float* W = (z == 0) ? Wq : (z == 1) ? Wk : Wv;
  bf16_t* out = wt + (size_t)z * CC * CC;
  __shared__ float tile[32][33];
  int tx = threadIdx.x;  // 0..31
  int ty = threadIdx.y;  // 0..7
  int n0 = blockIdx.x * 32;
  int c0 = blockIdx.y * 32;
#pragma unroll
  for (int k = 0; k < 4; ++k)
    tile[ty + k * 8][tx] = W[(size_t)(c0 + ty + k * 8) * CC + n0 + tx];
  __syncthreads();
#pragma unroll
  for (int k = 0; k < 4; ++k)
    out[(size_t)(n0 + ty + k * 8) * CC + c0 + tx] =
        (bf16_t)tile[tx][ty + k * 8];
}

// ---------------------------------------------------------------------------
// Kernel 3: QKV GEMM, 1D grid of 1152 = 8 XCD chunks x 144.
// Chunk-local order: n fastest within an m-row -> the 6 blocks sharing an
// A m-tile run consecutively on ONE XCD (L2 catches the re-reads).
// z=0: q (scaled by H^-1/2), z=1: k, z=2: v transposed.
// ---------------------------------------------------------------------------
__global__ __launch_bounds__(256) void qkv_gemm_kernel(
    const bf16_t* __restrict__ xbf, const bf16_t* __restrict__ wt,
    const float* __restrict__ bq, const float* __restrict__ bk,
    const float* __restrict__ bv, bf16_t* __restrict__ qb,
    bf16_t* __restrict__ kb, bf16_t* __restrict__ vt) {
  __shared__ bf16_t As0[4096], As1[4096], Bs0[4096], Bs1[4096];
  int bid = blockIdx.x;
  int work = (bid & 7) * 144 + (bid >> 3);  // 1152 = 8 * 144 (bijective)
  int z = work / 384;
  int rw = work - z * 384;
  int m0 = (rw / 6) * 128;
  int n0 = (rw % 6) * 128;

  f32x4 acc[4][4];
#pragma unroll
  for (int i = 0; i < 4; ++i)
#pragma unroll
    for (int j = 0; j < 4; ++j) acc[i][j] = (f32x4){0.f, 0.f, 0.f, 0.f};

  const bf16_t* A = xbf + (size_t)m0 * CC;
  const bf16_t* B = wt + (size_t)z * CC * CC + (size_t)n0 * CC;
  gemm_core(A, CC, B, CC, CC / 32, As0, As1, Bs0, Bs1, acc);

  int l = threadIdx.x & 63, w = threadIdx.x >> 6;
  int wr = (w >> 1) * 64, wc = (w & 1) * 64;
  const float* bias = (z == 0) ? bq : (z == 1) ? bk : bv;
  float scale = (z == 0) ? rsqrtf((float)CC) : 1.0f;

#pragma unroll
  for (int mi = 0; mi < 4; ++mi) {
#pragma unroll
    for (int ni = 0; ni < 4; ++ni) {
      int col = n0 + wc + ni * 16 + (l & 15);
      int rbase = m0 + wr + mi * 16 + (l >> 4) * 4;
      float bcol = bias[col];
#pragma unroll
      for (int r = 0; r < 4; ++r) {
        int m = rbase + r;
        float v = (acc[mi][ni][r] + bcol) * scale;
        bf16_t h = (bf16_t)v;
        if (z == 0) {
          qb[(size_t)m * CC + col] = h;
        } else if (z == 1) {
          kb[(size_t)m * CC + col] = h;
        } else {
          int b = m >> 11, tt = m & (TT - 1);
          vt[((size_t)b * CC + col) * TT + tt] = h;  // v^T: [B][H][T]
        }
      }
    }
  }
}

// ---------------------------------------------------------------------------
// Kernel 4: S = q k^T (scale folded into q), causal mask + (==0 -> -inf),
// stored fp16.  1D grid of 544 LIVE lower-tri blocks = 8 XCD chunks x 68;
// triangular decode (guarded sqrt).  Same-ti blocks consecutive -> q-tile
// L2 reuse.
// ---------------------------------------------------------------------------
__global__ __launch_bounds__(256) void s_gemm_kernel(
    const bf16_t* __restrict__ qb, const bf16_t* __restrict__ kb,
    _Float16* __restrict__ S) {
  __shared__ bf16_t As0[4096], As1[4096], Bs0[4096], Bs1[4096];
  int bid = blockIdx.x;
  int work = (bid & 7) * 68 + (bid >> 3);  // 544 = 8 * 68 (bijective)
  int b = work / 136;
  int t = work - b * 136;
  int ti = (int)((sqrtf(8.f * (float)t + 1.f) - 1.f) * 0.5f);
  while ((ti + 1) * (ti + 2) / 2 <= t) ++ti;  // guard fp rounding
  while (ti * (ti + 1) / 2 > t) --ti;
  int tj = t - ti * (ti + 1) / 2;
  int m0 = ti * 128, n0 = tj * 128;

  f32x4 acc[4][4];
#pragma unroll
  for (int i = 0; i < 4; ++i)
#pragma unroll
    for (int j = 0; j < 4; ++j) acc[i][j] = (f32x4){0.f, 0.f, 0.f, 0.f};

  const bf16_t* A = qb + ((size_t)b * TT + m0) * CC;
  const bf16_t* B = kb + ((size_t)b * TT + n0) * CC;
  gemm_core(A, CC, B, CC, CC / 32, As0, As1, Bs0, Bs1, acc);

  _Float16* Sb = S + (size_t)b * TT * TT;
  int l = threadIdx.x & 63, w = threadIdx.x >> 6;
  int wr = (w >> 1) * 64, wc = (w & 1) * 64;
#pragma unroll
  for (int mi = 0; mi < 4; ++mi) {
#pragma unroll
    for (int ni = 0; ni < 4; ++ni) {
      int j = n0 + wc + ni * 16 + (l & 15);
      int ibase = m0 + wr + mi * 16 + (l >> 4) * 4;
#pragma unroll
      for (int r = 0; r < 4; ++r) {
        int i = ibase + r;
        float v = acc[mi][ni][r];
        if (j > i || v == 0.0f) v = -INFINITY;  // causal + reference quirk
        Sb[(size_t)i * TT + j] = (_Float16)v;
      }
    }
  }
}

// ---------------------------------------------------------------------------
// Kernel 5: rowstat+normalize, wave-per-row (no LDS, no barriers).
// Block = 4 waves = 4 rows.  Per row: max M, L = sum exp(s-M); writes
// P = exp(s-M)/L as bf16 up to the 128-padded causal length.
// Lane l covers chunks {l, l+64, l+128, l+192} of 8 fp16 each.
// ---------------------------------------------------------------------------
__global__ __launch_bounds__(256) void rowstat_kernel(
    const _Float16* __restrict__ S, bf16_t* __restrict__ P) {
  int g = blockIdx.x * 4 + (threadIdx.x >> 6);  // global row id
  int b = g >> 11;
  int row = g & (TT - 1);
  int l = threadIdx.x & 63;
  const _Float16* s = S + ((size_t)b * TT + row) * TT;
  bf16_t* p = P + ((size_t)b * TT + row) * TT;
  int pe = ((row >> 7) + 1) << 7;  // padded causal length, multiple of 128

  float f[4][8];
#pragma unroll
  for (int c = 0; c < 4; ++c) {
    int j = (c * 64 + l) * 8;
    if (j < pe) {
      half8 h = *(const half8*)(s + j);
#pragma unroll
      for (int k = 0; k < 8; ++k) f[c][k] = (float)h[k];
    } else {
#pragma unroll
      for (int k = 0; k < 8; ++k) f[c][k] = -INFINITY;
    }
  }

  float m = f[0][0];
#pragma unroll
  for (int c = 0; c < 4; ++c)
#pragma unroll
    for (int k = 0; k < 8; ++k) m = fmaxf(m, f[c][k]);
#pragma unroll
  for (int off = 32; off > 0; off >>= 1) m = fmaxf(m, __shfl_xor(m, off));

  float e[4][8];
  float sum = 0.f;
#pragma unroll
  for (int c = 0; c < 4; ++c)
#pragma unroll
    for (int k = 0; k < 8; ++k) {
      e[c][k] = __expf(f[c][k] - m);  // exp(-inf)=0 for masked slots
      sum += e[c][k];
    }
#pragma unroll
  for (int off = 32; off > 0; off >>= 1) sum += __shfl_xor(sum, off);
  float inv = 1.0f / sum;

#pragma unroll
  for (int c = 0; c < 4; ++c) {
    int j = (c * 64 + l) * 8;
    if (j < pe) {
      bf16x8 o;
#pragma unroll
      for (int k = 0; k < 8; ++k) o[k] = (bf16_t)(e[c][k] * inv);
      *(bf16x8*)(p + j) = o;
    }
  }
}

// ---------------------------------------------------------------------------
// Kernel 6: O = P @ V   (A = P row-major [T][T], Bt = v^T [B][H][T]).
// 1D grid of 384 = 8 XCD chunks x 48.  Within a chunk: nj fastest (A-tile
// reuse), ti from the balance-paired permutation {15,0,14,1,...} so every
// chunk gets equal causal K work; heavy tiles lead each chunk.
// K-loop truncated at the causal boundary.
// ---------------------------------------------------------------------------
__global__ __launch_bounds__(256) void o_gemm_kernel(
    const bf16_t* __restrict__ P, const bf16_t* __restrict__ vt,
    float* __restrict__ out) {
  __shared__ bf16_t As0[4096], As1[4096], Bs0[4096], Bs1[4096];
  int bid = blockIdx.x;
  int work = (bid & 7) * 48 + (bid >> 3);  // 384 = 8 * 48 (bijective)
  int b = work / 96;
  int rw = work - b * 96;
  int i = rw / 6, nj = rw % 6;
  int ti = (i & 1) ? ((i - 1) >> 1) : (15 - (i >> 1));  // 15,0,14,1,...,8,7
  int m0 = ti * 128, n0 = nj * 128;

  f32x4 acc[4][4];
#pragma unroll
  for (int ii = 0; ii < 4; ++ii)
#pragma unroll
    for (int j = 0; j < 4; ++j) acc[ii][j] = (f32x4){0.f, 0.f, 0.f, 0.f};

  const bf16_t* A = P + ((size_t)b * TT + m0) * TT;
  const bf16_t* B = vt + ((size_t)b * CC + n0) * TT;
  gemm_core(A, TT, B, TT, (ti + 1) * 4, As0, As1, Bs0, Bs1, acc);

  float* Ob = out + (size_t)b * TT * CC;
  int l = threadIdx.x & 63, w = threadIdx.x >> 6;
  int wr = (w >> 1) * 64, wc = (w & 1) * 64;
#pragma unroll
  for (int mi = 0; mi < 4; ++mi) {
#pragma unroll
    for (int ni = 0; ni < 4; ++ni) {
      int col = n0 + wc + ni * 16 + (l & 15);
      int ibase = m0 + wr + mi * 16 + (l >> 4) * 4;
#pragma unroll
      for (int r = 0; r < 4; ++r)
        Ob[(size_t)(ibase + r) * CC + col] = acc[mi][ni][r];
    }
  }
}

// ---------------------------------------------------------------------------
extern "C" void kernel_launch(void* const* d_in, const int* in_sizes, int n_in,
                              void* d_out, int out_size, void* d_ws,
                              size_t ws_size, hipStream_t stream) {
  const float* x = (const float*)d_in[0];
  const float* Wq = (const float*)d_in[1];
  const float* bq = (const float*)d_in[2];
  const float* Wk = (const float*)d_in[3];
  const float* bk = (const float*)d_in[4];
  const float* Wv = (const float*)d_in[5];
  const float* bv = (const float*)d_in[6];
  float* out = (float*)d_out;

  char* ws = (char*)d_ws;
  size_t off = 0;
  auto carve = [&](size_t bytes) -> char* {
    char* p = ws + off;
    off += (bytes + 255) & ~(size_t)255;
    return p;
  };
  const size_t M = (size_t)BB * TT;  // 8192
  bf16_t* xbf = (bf16_t*)carve(M * CC * 2);            // 12.6 MB
  bf16_t* wt  = (bf16_t*)carve(3ull * CC * CC * 2);    // 3.5 MB
  bf16_t* qb  = (bf16_t*)carve(M * CC * 2);            // 12.6 MB
  bf16_t* kb  = (bf16_t*)carve(M * CC * 2);            // 12.6 MB
  bf16_t* vt  = (bf16_t*)carve(M * CC * 2);            // 12.6 MB (as [B][H][T])
  _Float16* S = (_Float16*)carve((size_t)BB * TT * TT * 2);  // 33.5 MB
  bf16_t* P   = (bf16_t*)carve((size_t)BB * TT * TT * 2);    // 33.5 MB
  (void)off; (void)ws_size;

  // 1+2: input prep
  cast_x_kernel<<<(M * CC / 8 + 255) / 256, 256, 0, stream>>>(x, xbf);
  transpose_w_kernel<<<dim3(CC / 32, CC / 32, 3), dim3(32, 8, 1), 0, stream>>>(
      Wq, Wk, Wv, wt);
  // 3: q,k,v
  qkv_gemm_kernel<<<1152, 256, 0, stream>>>(xbf, wt, bq, bk, bv, qb, kb, vt);
  // 4: S = q k^T (lower-tri blocks, fp16)
  s_gemm_kernel<<<544, 256, 0, stream>>>(qb, kb, S);
  // 5: softmax rows -> P (bf16, zero-padded)
  rowstat_kernel<<<BB * TT / 4, 256, 0, stream>>>(S, P);
  // 6: O = P V
  o_gemm_kernel<<<384, 256, 0, stream>>>(P, vt, out);
}

// Round 5
// 221.831 us; speedup vs baseline: 1.1278x; 1.0105x over previous
//
#include <hip/hip_runtime.h>
#include <math.h>

// ---------------------------------------------------------------------------
// AttentionLayer: out = softmax(mask(q k^T * scale)) @ v,  q/k/v = x@W + b
// B=4, T=2048, C=H=768.  bf16 MFMA (16x16x32), fp32 accumulate.
// R8 (this round), from R7 post-mortem (224 us; qkv 76.6 us invariant across
//     THREE pipeline structures => schedule not binding; counters show
//     (a) 3.54M LDS conflicts/dispatch = 4 cyc per ds_read_b128: old swizzle
//     p=q^(r&3) leaves rows {r,r+4,r+8,r+12} on the same bank quad (row=64B
//     =16 banks, so only r&1 and the chunk matter) -> 4-way conflict;
//     (b) occupancy 17.7% = 3 waves/SIMD cap from 84 VGPR + 64 AGPR = 148):
//   - swizzle -> swz(r) = (r&3)^((r>>2)&3): the 4-aliasing row group now
//     gets 4 distinct chunks; worst case 2-way = free (m136).  Same XOR
//     involution on stage (pre-swizzled global source) and read sides.
//   - __launch_bounds__(256,4) on the three GEMM kernels: cap 128 unified
//     regs/wave -> 4 waves/SIMD (acc=64 AGPR + <=64 VGPR).
//   - Everything else identical to R7 (R3 static dbuf core, XCD-chunked 1D
//     grids, live-triangular s_gemm, balance-paired o_gemm, wave-row rowstat).
// ---------------------------------------------------------------------------

#define BB 4
#define TT 2048
#define CC 768

typedef __bf16 bf16_t;
typedef __bf16 bf16x8 __attribute__((ext_vector_type(8)));
typedef _Float16 half8 __attribute__((ext_vector_type(8)));
typedef float f32x4 __attribute__((ext_vector_type(4)));

// ---------------------------------------------------------------------------
// async global->LDS 16B copy (wave-uniform LDS base + lane*16 implicit)
// ---------------------------------------------------------------------------
__device__ __forceinline__ void async_load16(void* lds, const void* g) {
  __builtin_amdgcn_global_load_lds(
      (const __attribute__((address_space(1))) void*)g,
      (__attribute__((address_space(3))) void*)lds, 16, 0, 0);
}

// Chunk swizzle for a 128x32 bf16 tile stored as 4x16B chunks per 64B row.
// Bank quad of (row r, physical chunk p) = (4*(r&1) + p) mod 8 -> rows with
// equal (r&1) alias unless p differs.  swz spreads the r&3 and (r>>2)&3
// groups so any 16 consecutive rows hit each chunk slot at most 2x (free).
__device__ __forceinline__ int swz4(int r) {
  return (r & 3) ^ ((r >> 2) & 3);
}

// Stage a 128x32 bf16 tile (row-major, row stride ld elements) into LDS.
// LDS layout: row-major 128x32, 8-elem chunks XOR-swizzled within a row:
// physical chunk p of row r holds logical chunk p ^ swz4(r) (pre-swizzled
// global source; LDS destination stays linear as global_load_lds requires).
__device__ __forceinline__ void stage_tile(const bf16_t* __restrict__ g0,
                                           int ld, bf16_t* lds, int t) {
  int w = t >> 6, l = t & 63;
#pragma unroll
  for (int i = 0; i < 2; ++i) {
    int c = i * 256 + w * 64 + l;   // linear 16B-chunk id in LDS
    int row = c >> 2;
    int p = c & 3;
    int q = p ^ swz4(row);          // logical chunk to fetch
    async_load16(lds + i * 2048 + w * 512,  // wave-uniform base (elements)
                 g0 + row * ld + q * 8);
  }
}

// Read one MFMA fragment (8 bf16, 16B) for logical (row r, k-chunk q).
__device__ __forceinline__ bf16x8 read_frag(const bf16_t* lds, int r, int q) {
  int p = q ^ swz4(r);
  return *(const bf16x8*)(lds + r * 32 + p * 8);
}

// One 128x128x32 MFMA step from a published LDS buffer pair.
__device__ __forceinline__ void mfma_tile(const bf16_t* Ab, const bf16_t* Bb,
                                          int wr, int wc, int l,
                                          f32x4 acc[4][4]) {
  bf16x8 af[4], bfr[4];
  int q = l >> 4;
#pragma unroll
  for (int i = 0; i < 4; ++i) {
    af[i] = read_frag(Ab, wr + i * 16 + (l & 15), q);
    bfr[i] = read_frag(Bb, wc + i * 16 + (l & 15), q);
  }
#pragma unroll
  for (int mi = 0; mi < 4; ++mi)
#pragma unroll
    for (int ni = 0; ni < 4; ++ni)
      acc[mi][ni] = __builtin_amdgcn_mfma_f32_16x16x32_bf16(
          af[mi], bfr[ni], acc[mi][ni], 0, 0, 0);
}

// Core: C[128x128] += A[128xK] * B^T.  kTiles must be EVEN.
// R3-proven unroll-2 static double-buffer: one barrier per k-tile; each async
// stage has a full MFMA phase in flight before the barrier that drains it.
// Plain __syncthreads (compiler manages waitcnt); 32 KB LDS.
__device__ __forceinline__ void gemm_core(const bf16_t* __restrict__ A, int lda,
                                          const bf16_t* __restrict__ B, int ldb,
                                          int kTiles, bf16_t* As0, bf16_t* As1,
                                          bf16_t* Bs0, bf16_t* Bs1,
                                          f32x4 acc[4][4]) {
  int t = threadIdx.x;
  int l = t & 63;
  int w = t >> 6;
  int wr = (w >> 1) * 64;  // wave row offset in 128-tile
  int wc = (w & 1) * 64;   // wave col offset

  stage_tile(A, lda, As0, t);  // k-tile 0 -> buf0
  stage_tile(B, ldb, Bs0, t);

  for (int kt = 0; kt < kTiles; kt += 2) {
    __syncthreads();  // publish buf0(kt); prior buf1 reads complete
    stage_tile(A + (kt + 1) * 32, lda, As1, t);   // prefetch kt+1
    stage_tile(B + (kt + 1) * 32, ldb, Bs1, t);
    mfma_tile(As0, Bs0, wr, wc, l, acc);
    __syncthreads();  // publish buf1(kt+1); buf0 reads complete
    if (kt + 2 < kTiles) {
      stage_tile(A + (kt + 2) * 32, lda, As0, t);  // prefetch kt+2
      stage_tile(B + (kt + 2) * 32, ldb, Bs0, t);
    }
    mfma_tile(As1, Bs1, wr, wc, l, acc);
  }
}

// C/D layout (m89-verified): col = lane&15, row = (lane>>4)*4 + reg.

// ---------------------------------------------------------------------------
// Kernel 1: cast x (fp32) -> bf16, 8 elems/thread
// ---------------------------------------------------------------------------
__global__ __launch_bounds__(256) void cast_x_kernel(
    const float* __restrict__ x, bf16_t* __restrict__ xbf) {
  int i = blockIdx.x * 256 + threadIdx.x;
  const float4* xin = (const float4*)x;
  float4 a = xin[i * 2];
  float4 b = xin[i * 2 + 1];
  bf16_t tmp[8];
  tmp[0] = (bf16_t)a.x; tmp[1] = (bf16_t)a.y;
  tmp[2] = (bf16_t)a.z; tmp[3] = (bf16_t)a.w;
  tmp[4] = (bf16_t)b.x; tmp[5] = (bf16_t)b.y;
  tmp[6] = (bf16_t)b.z; tmp[7] = (bf16_t)b.w;
  *(uint4*)(xbf + (size_t)i * 8) = *(const uint4*)tmp;
}

// ---------------------------------------------------------------------------
// Kernel 2: transpose+cast the three weight matrices [C][H] -> bf16 [H][C]
// ---------------------------------------------------------------------------
__global__ __launch_bounds__(256) void transpose_w_kernel(
    const float* __restrict__ Wq, const float* __restrict__ Wk,
    const float* __restrict__ Wv, bf16_t* __restrict__ wt) {
  int z = blockIdx.z;
  const float* W = (z == 0) ? Wq : (z == 1) ? Wk : Wv;
  bf16_t* out = wt + (size_t)z * CC * CC;
  __shared__ float tile[32][33];
  int tx = threadIdx.x;  // 0..31
  int ty = threadIdx.y;  // 0..7
  int n0 = blockIdx.x * 32;
  int c0 = blockIdx.y * 32;
#pragma unroll
  for (int k = 0; k < 4; ++k)
    tile[ty + k * 8][tx] = W[(size_t)(c0 + ty + k * 8) * CC + n0 + tx];
  __syncthreads();
#pragma unroll
  for (int k = 0; k < 4; ++k)
    out[(size_t)(n0 + ty + k * 8) * CC + c0 + tx] =
        (bf16_t)tile[tx][ty + k * 8];
}

// ---------------------------------------------------------------------------
// Kernel 3: QKV GEMM, 1D grid of 1152 = 8 XCD chunks x 144.
// Chunk-local order: n fastest within an m-row -> the 6 blocks sharing an
// A m-tile run consecutively on ONE XCD (L2 catches the re-reads).
// z=0: q (scaled by H^-1/2), z=1: k, z=2: v transposed.
// ---------------------------------------------------------------------------
__global__ __launch_bounds__(256, 4) void qkv_gemm_kernel(
    const bf16_t* __restrict__ xbf, const bf16_t* __restrict__ wt,
    const float* __restrict__ bq, const float* __restrict__ bk,
    const float* __restrict__ bv, bf16_t* __restrict__ qb,
    bf16_t* __restrict__ kb, bf16_t* __restrict__ vt) {
  __shared__ bf16_t As0[4096], As1[4096], Bs0[4096], Bs1[4096];
  int bid = blockIdx.x;
  int work = (bid & 7) * 144 + (bid >> 3);  // 1152 = 8 * 144 (bijective)
  int z = work / 384;
  int rw = work - z * 384;
  int m0 = (rw / 6) * 128;
  int n0 = (rw % 6) * 128;

  f32x4 acc[4][4];
#pragma unroll
  for (int i = 0; i < 4; ++i)
#pragma unroll
    for (int j = 0; j < 4; ++j) acc[i][j] = (f32x4){0.f, 0.f, 0.f, 0.f};

  const bf16_t* A = xbf + (size_t)m0 * CC;
  const bf16_t* B = wt + (size_t)z * CC * CC + (size_t)n0 * CC;
  gemm_core(A, CC, B, CC, CC / 32, As0, As1, Bs0, Bs1, acc);

  int l = threadIdx.x & 63, w = threadIdx.x >> 6;
  int wr = (w >> 1) * 64, wc = (w & 1) * 64;
  const float* bias = (z == 0) ? bq : (z == 1) ? bk : bv;
  float scale = (z == 0) ? rsqrtf((float)CC) : 1.0f;

#pragma unroll
  for (int mi = 0; mi < 4; ++mi) {
#pragma unroll
    for (int ni = 0; ni < 4; ++ni) {
      int col = n0 + wc + ni * 16 + (l & 15);
      int rbase = m0 + wr + mi * 16 + (l >> 4) * 4;
      float bcol = bias[col];
#pragma unroll
      for (int r = 0; r < 4; ++r) {
        int m = rbase + r;
        float v = (acc[mi][ni][r] + bcol) * scale;
        bf16_t h = (bf16_t)v;
        if (z == 0) {
          qb[(size_t)m * CC + col] = h;
        } else if (z == 1) {
          kb[(size_t)m * CC + col] = h;
        } else {
          int b = m >> 11, tt = m & (TT - 1);
          vt[((size_t)b * CC + col) * TT + tt] = h;  // v^T: [B][H][T]
        }
      }
    }
  }
}

// ---------------------------------------------------------------------------
// Kernel 4: S = q k^T (scale folded into q), causal mask + (==0 -> -inf),
// stored fp16.  1D grid of 544 LIVE lower-tri blocks = 8 XCD chunks x 68;
// triangular decode (guarded sqrt).  Same-ti blocks consecutive -> q-tile
// L2 reuse.
// ---------------------------------------------------------------------------
__global__ __launch_bounds__(256, 4) void s_gemm_kernel(
    const bf16_t* __restrict__ qb, const bf16_t* __restrict__ kb,
    _Float16* __restrict__ S) {
  __shared__ bf16_t As0[4096], As1[4096], Bs0[4096], Bs1[4096];
  int bid = blockIdx.x;
  int work = (bid & 7) * 68 + (bid >> 3);  // 544 = 8 * 68 (bijective)
  int b = work / 136;
  int t = work - b * 136;
  int ti = (int)((sqrtf(8.f * (float)t + 1.f) - 1.f) * 0.5f);
  while ((ti + 1) * (ti + 2) / 2 <= t) ++ti;  // guard fp rounding
  while (ti * (ti + 1) / 2 > t) --ti;
  int tj = t - ti * (ti + 1) / 2;
  int m0 = ti * 128, n0 = tj * 128;

  f32x4 acc[4][4];
#pragma unroll
  for (int i = 0; i < 4; ++i)
#pragma unroll
    for (int j = 0; j < 4; ++j) acc[i][j] = (f32x4){0.f, 0.f, 0.f, 0.f};

  const bf16_t* A = qb + ((size_t)b * TT + m0) * CC;
  const bf16_t* B = kb + ((size_t)b * TT + n0) * CC;
  gemm_core(A, CC, B, CC, CC / 32, As0, As1, Bs0, Bs1, acc);

  _Float16* Sb = S + (size_t)b * TT * TT;
  int l = threadIdx.x & 63, w = threadIdx.x >> 6;
  int wr = (w >> 1) * 64, wc = (w & 1) * 64;
#pragma unroll
  for (int mi = 0; mi < 4; ++mi) {
#pragma unroll
    for (int ni = 0; ni < 4; ++ni) {
      int j = n0 + wc + ni * 16 + (l & 15);
      int ibase = m0 + wr + mi * 16 + (l >> 4) * 4;
#pragma unroll
      for (int r = 0; r < 4; ++r) {
        int i = ibase + r;
        float v = acc[mi][ni][r];
        if (j > i || v == 0.0f) v = -INFINITY;  // causal + reference quirk
        Sb[(size_t)i * TT + j] = (_Float16)v;
      }
    }
  }
}

// ---------------------------------------------------------------------------
// Kernel 5: rowstat+normalize, wave-per-row (no LDS, no barriers).
// Block = 4 waves = 4 rows.  Per row: max M, L = sum exp(s-M); writes
// P = exp(s-M)/L as bf16 up to the 128-padded causal length.
// Lane l covers chunks {l, l+64, l+128, l+192} of 8 fp16 each.
// ---------------------------------------------------------------------------
__global__ __launch_bounds__(256) void rowstat_kernel(
    const _Float16* __restrict__ S, bf16_t* __restrict__ P) {
  int g = blockIdx.x * 4 + (threadIdx.x >> 6);  // global row id
  int b = g >> 11;
  int row = g & (TT - 1);
  int l = threadIdx.x & 63;
  const _Float16* s = S + ((size_t)b * TT + row) * TT;
  bf16_t* p = P + ((size_t)b * TT + row) * TT;
  int pe = ((row >> 7) + 1) << 7;  // padded causal length, multiple of 128

  float f[4][8];
#pragma unroll
  for (int c = 0; c < 4; ++c) {
    int j = (c * 64 + l) * 8;
    if (j < pe) {
      half8 h = *(const half8*)(s + j);
#pragma unroll
      for (int k = 0; k < 8; ++k) f[c][k] = (float)h[k];
    } else {
#pragma unroll
      for (int k = 0; k < 8; ++k) f[c][k] = -INFINITY;
    }
  }

  float m = f[0][0];
#pragma unroll
  for (int c = 0; c < 4; ++c)
#pragma unroll
    for (int k = 0; k < 8; ++k) m = fmaxf(m, f[c][k]);
#pragma unroll
  for (int off = 32; off > 0; off >>= 1) m = fmaxf(m, __shfl_xor(m, off));

  float e[4][8];
  float sum = 0.f;
#pragma unroll
  for (int c = 0; c < 4; ++c)
#pragma unroll
    for (int k = 0; k < 8; ++k) {
      e[c][k] = __expf(f[c][k] - m);  // exp(-inf)=0 for masked slots
      sum += e[c][k];
    }
#pragma unroll
  for (int off = 32; off > 0; off >>= 1) sum += __shfl_xor(sum, off);
  float inv = 1.0f / sum;

#pragma unroll
  for (int c = 0; c < 4; ++c) {
    int j = (c * 64 + l) * 8;
    if (j < pe) {
      bf16x8 o;
#pragma unroll
      for (int k = 0; k < 8; ++k) o[k] = (bf16_t)(e[c][k] * inv);
      *(bf16x8*)(p + j) = o;
    }
  }
}

// ---------------------------------------------------------------------------
// Kernel 6: O = P @ V   (A = P row-major [T][T], Bt = v^T [B][H][T]).
// 1D grid of 384 = 8 XCD chunks x 48.  Within a chunk: nj fastest (A-tile
// reuse), ti from the balance-paired permutation {15,0,14,1,...} so every
// chunk gets equal causal K work; heavy tiles lead each chunk.
// K-loop truncated at the causal boundary.
// ---------------------------------------------------------------------------
__global__ __launch_bounds__(256, 4) void o_gemm_kernel(
    const bf16_t* __restrict__ P, const bf16_t* __restrict__ vt,
    float* __restrict__ out) {
  __shared__ bf16_t As0[4096], As1[4096], Bs0[4096], Bs1[4096];
  int bid = blockIdx.x;
  int work = (bid & 7) * 48 + (bid >> 3);  // 384 = 8 * 48 (bijective)
  int b = work / 96;
  int rw = work - b * 96;
  int i = rw / 6, nj = rw % 6;
  int ti = (i & 1) ? ((i - 1) >> 1) : (15 - (i >> 1));  // 15,0,14,1,...,8,7
  int m0 = ti * 128, n0 = nj * 128;

  f32x4 acc[4][4];
#pragma unroll
  for (int ii = 0; ii < 4; ++ii)
#pragma unroll
    for (int j = 0; j < 4; ++j) acc[ii][j] = (f32x4){0.f, 0.f, 0.f, 0.f};

  const bf16_t* A = P + ((size_t)b * TT + m0) * TT;
  const bf16_t* B = vt + ((size_t)b * CC + n0) * TT;
  gemm_core(A, TT, B, TT, (ti + 1) * 4, As0, As1, Bs0, Bs1, acc);

  float* Ob = out + (size_t)b * TT * CC;
  int l = threadIdx.x & 63, w = threadIdx.x >> 6;
  int wr = (w >> 1) * 64, wc = (w & 1) * 64;
#pragma unroll
  for (int mi = 0; mi < 4; ++mi) {
#pragma unroll
    for (int ni = 0; ni < 4; ++ni) {
      int col = n0 + wc + ni * 16 + (l & 15);
      int ibase = m0 + wr + mi * 16 + (l >> 4) * 4;
#pragma unroll
      for (int r = 0; r < 4; ++r)
        Ob[(size_t)(ibase + r) * CC + col] = acc[mi][ni][r];
    }
  }
}

// ---------------------------------------------------------------------------
extern "C" void kernel_launch(void* const* d_in, const int* in_sizes, int n_in,
                              void* d_out, int out_size, void* d_ws,
                              size_t ws_size, hipStream_t stream) {
  const float* x = (const float*)d_in[0];
  const float* Wq = (const float*)d_in[1];
  const float* bq = (const float*)d_in[2];
  const float* Wk = (const float*)d_in[3];
  const float* bk = (const float*)d_in[4];
  const float* Wv = (const float*)d_in[5];
  const float* bv = (const float*)d_in[6];
  float* out = (float*)d_out;

  char* ws = (char*)d_ws;
  size_t off = 0;
  auto carve = [&](size_t bytes) -> char* {
    char* p = ws + off;
    off += (bytes + 255) & ~(size_t)255;
    return p;
  };
  const size_t M = (size_t)BB * TT;  // 8192
  bf16_t* xbf = (bf16_t*)carve(M * CC * 2);            // 12.6 MB
  bf16_t* wt  = (bf16_t*)carve(3ull * CC * CC * 2);    // 3.5 MB
  bf16_t* qb  = (bf16_t*)carve(M * CC * 2);            // 12.6 MB
  bf16_t* kb  = (bf16_t*)carve(M * CC * 2);            // 12.6 MB
  bf16_t* vt  = (bf16_t*)carve(M * CC * 2);            // 12.6 MB (as [B][H][T])
  _Float16* S = (_Float16*)carve((size_t)BB * TT * TT * 2);  // 33.5 MB
  bf16_t* P   = (bf16_t*)carve((size_t)BB * TT * TT * 2);    // 33.5 MB
  (void)off; (void)ws_size;

  // 1+2: input prep
  cast_x_kernel<<<(M * CC / 8 + 255) / 256, 256, 0, stream>>>(x, xbf);
  transpose_w_kernel<<<dim3(CC / 32, CC / 32, 3), dim3(32, 8, 1), 0, stream>>>(
      Wq, Wk, Wv, wt);
  // 3: q,k,v
  qkv_gemm_kernel<<<1152, 256, 0, stream>>>(xbf, wt, bq, bk, bv, qb, kb, vt);
  // 4: S = q k^T (lower-tri blocks, fp16)
  s_gemm_kernel<<<544, 256, 0, stream>>>(qb, kb, S);
  // 5: softmax rows -> P (bf16, zero-padded)
  rowstat_kernel<<<BB * TT / 4, 256, 0, stream>>>(S, P);
  // 6: O = P V
  o_gemm_kernel<<<384, 256, 0, stream>>>(P, vt, out);
}

// Round 6
// 197.286 us; speedup vs baseline: 1.2681x; 1.1244x over previous
//
#include <hip/hip_runtime.h>
#include <math.h>

// ---------------------------------------------------------------------------
// AttentionLayer: out = softmax(mask(q k^T * scale)) @ v,  q/k/v = x@W + b
// B=4, T=2048, C=H=768.  bf16 MFMA (16x16x32), fp32 accumulate.
// R9 (this round), from R8 post-mortem (221.8 us; qkv REGRESSED 76.6->96 via
//     launch_bounds(256,4) [VALUBusy 22->8.4, WRITE_SIZE +10MB], while s/o
//     GAINED ~22 us from the same flag; SQ_LDS_BANK_CONFLICT invariant at
//     exactly 3538944 across two different swizzles => it's the structural
//     ds_read_b128 wave64 serialization floor, not a lever):
//   - qkv: revert to plain launch_bounds(256) (R7 config).  s/o keep (256,4).
//   - qkv z==2 epilogue: vt was 64x 2B stores/thread at 4KB stride.  Now
//     round-trips the 128x128 tile through the freed 32KB LDS in [col][m]
//     order (chunk-XOR swizzled), then writes 16B/lane = 4x256B contiguous
//     segments per wave-instr.
//   - Everything else identical to R8.
// ---------------------------------------------------------------------------

#define BB 4
#define TT 2048
#define CC 768

typedef __bf16 bf16_t;
typedef __bf16 bf16x8 __attribute__((ext_vector_type(8)));
typedef _Float16 half8 __attribute__((ext_vector_type(8)));
typedef float f32x4 __attribute__((ext_vector_type(4)));

// ---------------------------------------------------------------------------
// async global->LDS 16B copy (wave-uniform LDS base + lane*16 implicit)
// ---------------------------------------------------------------------------
__device__ __forceinline__ void async_load16(void* lds, const void* g) {
  __builtin_amdgcn_global_load_lds(
      (const __attribute__((address_space(1))) void*)g,
      (__attribute__((address_space(3))) void*)lds, 16, 0, 0);
}

// Chunk swizzle for a 128x32 bf16 tile stored as 4x16B chunks per 64B row.
// (Bank-uniform at wave level; kept from R8 — measured-identical to R7's.)
__device__ __forceinline__ int swz4(int r) {
  return (r & 3) ^ ((r >> 2) & 3);
}

// Stage a 128x32 bf16 tile (row-major, row stride ld elements) into LDS.
// LDS layout: row-major 128x32, 8-elem chunks XOR-swizzled within a row:
// physical chunk p of row r holds logical chunk p ^ swz4(r) (pre-swizzled
// global source; LDS destination stays linear as global_load_lds requires).
__device__ __forceinline__ void stage_tile(const bf16_t* __restrict__ g0,
                                           int ld, bf16_t* lds, int t) {
  int w = t >> 6, l = t & 63;
#pragma unroll
  for (int i = 0; i < 2; ++i) {
    int c = i * 256 + w * 64 + l;   // linear 16B-chunk id in LDS
    int row = c >> 2;
    int p = c & 3;
    int q = p ^ swz4(row);          // logical chunk to fetch
    async_load16(lds + i * 2048 + w * 512,  // wave-uniform base (elements)
                 g0 + row * ld + q * 8);
  }
}

// Read one MFMA fragment (8 bf16, 16B) for logical (row r, k-chunk q).
__device__ __forceinline__ bf16x8 read_frag(const bf16_t* lds, int r, int q) {
  int p = q ^ swz4(r);
  return *(const bf16x8*)(lds + r * 32 + p * 8);
}

// One 128x128x32 MFMA step from a published LDS buffer pair.
__device__ __forceinline__ void mfma_tile(const bf16_t* Ab, const bf16_t* Bb,
                                          int wr, int wc, int l,
                                          f32x4 acc[4][4]) {
  bf16x8 af[4], bfr[4];
  int q = l >> 4;
#pragma unroll
  for (int i = 0; i < 4; ++i) {
    af[i] = read_frag(Ab, wr + i * 16 + (l & 15), q);
    bfr[i] = read_frag(Bb, wc + i * 16 + (l & 15), q);
  }
#pragma unroll
  for (int mi = 0; mi < 4; ++mi)
#pragma unroll
    for (int ni = 0; ni < 4; ++ni)
      acc[mi][ni] = __builtin_amdgcn_mfma_f32_16x16x32_bf16(
          af[mi], bfr[ni], acc[mi][ni], 0, 0, 0);
}

// Core: C[128x128] += A[128xK] * B^T.  kTiles must be EVEN.
// R3-proven unroll-2 static double-buffer: one barrier per k-tile; each async
// stage has a full MFMA phase in flight before the barrier that drains it.
// Plain __syncthreads (compiler manages waitcnt); 32 KB LDS.
__device__ __forceinline__ void gemm_core(const bf16_t* __restrict__ A, int lda,
                                          const bf16_t* __restrict__ B, int ldb,
                                          int kTiles, bf16_t* As0, bf16_t* As1,
                                          bf16_t* Bs0, bf16_t* Bs1,
                                          f32x4 acc[4][4]) {
  int t = threadIdx.x;
  int l = t & 63;
  int w = t >> 6;
  int wr = (w >> 1) * 64;  // wave row offset in 128-tile
  int wc = (w & 1) * 64;   // wave col offset

  stage_tile(A, lda, As0, t);  // k-tile 0 -> buf0
  stage_tile(B, ldb, Bs0, t);

  for (int kt = 0; kt < kTiles; kt += 2) {
    __syncthreads();  // publish buf0(kt); prior buf1 reads complete
    stage_tile(A + (kt + 1) * 32, lda, As1, t);   // prefetch kt+1
    stage_tile(B + (kt + 1) * 32, ldb, Bs1, t);
    mfma_tile(As0, Bs0, wr, wc, l, acc);
    __syncthreads();  // publish buf1(kt+1); buf0 reads complete
    if (kt + 2 < kTiles) {
      stage_tile(A + (kt + 2) * 32, lda, As0, t);  // prefetch kt+2
      stage_tile(B + (kt + 2) * 32, ldb, Bs0, t);
    }
    mfma_tile(As1, Bs1, wr, wc, l, acc);
  }
}

// C/D layout (m89-verified): col = lane&15, row = (lane>>4)*4 + reg.

// ---------------------------------------------------------------------------
// Kernel 1: cast x (fp32) -> bf16, 8 elems/thread
// ---------------------------------------------------------------------------
__global__ __launch_bounds__(256) void cast_x_kernel(
    const float* __restrict__ x, bf16_t* __restrict__ xbf) {
  int i = blockIdx.x * 256 + threadIdx.x;
  const float4* xin = (const float4*)x;
  float4 a = xin[i * 2];
  float4 b = xin[i * 2 + 1];
  bf16_t tmp[8];
  tmp[0] = (bf16_t)a.x; tmp[1] = (bf16_t)a.y;
  tmp[2] = (bf16_t)a.z; tmp[3] = (bf16_t)a.w;
  tmp[4] = (bf16_t)b.x; tmp[5] = (bf16_t)b.y;
  tmp[6] = (bf16_t)b.z; tmp[7] = (bf16_t)b.w;
  *(uint4*)(xbf + (size_t)i * 8) = *(const uint4*)tmp;
}

// ---------------------------------------------------------------------------
// Kernel 2: transpose+cast the three weight matrices [C][H] -> bf16 [H][C]
// ---------------------------------------------------------------------------
__global__ __launch_bounds__(256) void transpose_w_kernel(
    const float* __restrict__ Wq, const float* __restrict__ Wk,
    const float* __restrict__ Wv, bf16_t* __restrict__ wt) {
  int z = blockIdx.z;
  const float* W = (z == 0) ? Wq : (z == 1) ? Wk : Wv;
  bf16_t* out = wt + (size_t)z * CC * CC;
  __shared__ float tile[32][33];
  int tx = threadIdx.x;  // 0..31
  int ty = threadIdx.y;  // 0..7
  int n0 = blockIdx.x * 32;
  int c0 = blockIdx.y * 32;
#pragma unroll
  for (int k = 0; k < 4; ++k)
    tile[ty + k * 8][tx] = W[(size_t)(c0 + ty + k * 8) * CC + n0 + tx];
  __syncthreads();
#pragma unroll
  for (int k = 0; k < 4; ++k)
    out[(size_t)(n0 + ty + k * 8) * CC + c0 + tx] =
        (bf16_t)tile[tx][ty + k * 8];
}

// ---------------------------------------------------------------------------
// Kernel 3: QKV GEMM, 1D grid of 1152 = 8 XCD chunks x 144.
// Chunk-local order: n fastest within an m-row -> the 6 blocks sharing an
// A m-tile run consecutively on ONE XCD (L2 catches the re-reads).
// z=0: q (scaled by H^-1/2), z=1: k, z=2: v transposed (LDS-coalesced).
// ---------------------------------------------------------------------------
__global__ __launch_bounds__(256) void qkv_gemm_kernel(
    const bf16_t* __restrict__ xbf, const bf16_t* __restrict__ wt,
    const float* __restrict__ bq, const float* __restrict__ bk,
    const float* __restrict__ bv, bf16_t* __restrict__ qb,
    bf16_t* __restrict__ kb, bf16_t* __restrict__ vt) {
  __shared__ bf16_t smem[16384];  // 32KB: gemm dbuf, then vt transpose buf
  int bid = blockIdx.x;
  int work = (bid & 7) * 144 + (bid >> 3);  // 1152 = 8 * 144 (bijective)
  int z = work / 384;
  int rw = work - z * 384;
  int m0 = (rw / 6) * 128;
  int n0 = (rw % 6) * 128;

  f32x4 acc[4][4];
#pragma unroll
  for (int i = 0; i < 4; ++i)
#pragma unroll
    for (int j = 0; j < 4; ++j) acc[i][j] = (f32x4){0.f, 0.f, 0.f, 0.f};

  const bf16_t* A = xbf + (size_t)m0 * CC;
  const bf16_t* B = wt + (size_t)z * CC * CC + (size_t)n0 * CC;
  gemm_core(A, CC, B, CC, CC / 32, smem, smem + 4096, smem + 8192,
            smem + 12288, acc);

  int t = threadIdx.x;
  int l = t & 63, w = t >> 6;
  int wr = (w >> 1) * 64, wc = (w & 1) * 64;
  const float* bias = (z == 0) ? bq : (z == 1) ? bk : bv;

  if (z < 2) {
    float scale = (z == 0) ? rsqrtf((float)CC) : 1.0f;
    bf16_t* dst = (z == 0) ? qb : kb;
#pragma unroll
    for (int mi = 0; mi < 4; ++mi) {
#pragma unroll
      for (int ni = 0; ni < 4; ++ni) {
        int col = n0 + wc + ni * 16 + (l & 15);
        int rbase = m0 + wr + mi * 16 + (l >> 4) * 4;
        float bcol = bias[col];
#pragma unroll
        for (int r = 0; r < 4; ++r) {
          float v = (acc[mi][ni][r] + bcol) * scale;
          dst[(size_t)(rbase + r) * CC + col] = (bf16_t)v;
        }
      }
    }
  } else {
    // v^T: stage the 128x128 tile into LDS as [col][m] (chunk-XOR swizzled),
    // then write coalesced 16B/lane (4x256B contiguous segments per instr).
    __syncthreads();  // all waves done reading gemm LDS buffers
#pragma unroll
    for (int mi = 0; mi < 4; ++mi) {
#pragma unroll
      for (int ni = 0; ni < 4; ++ni) {
        int cl = wc + ni * 16 + (l & 15);
        int mlb = wr + mi * 16 + (l >> 4) * 4;
        float bcol = bias[n0 + cl];
        bf16_t t4[4];
#pragma unroll
        for (int r = 0; r < 4; ++r) t4[r] = (bf16_t)(acc[mi][ni][r] + bcol);
        // element index with chunk swizzle: chunk_log = mlb>>3 (r's stay
        // inside one 8-elem chunk since mlb%8 is 0 or 4)
        int e = cl * 128 + (((mlb >> 3) ^ (cl & 15)) << 3) + (mlb & 7);
        *(uint2*)((unsigned int*)smem + (e >> 1)) = *(const uint2*)t4;
      }
    }
    __syncthreads();
    int b = m0 >> 11;
    int tt0 = m0 & (TT - 1);
#pragma unroll
    for (int g = 0; g < 8; ++g) {
      int cl = g * 16 + (t >> 4);   // 0..127 over 8 iterations
      int ck = t & 15;              // logical 8-elem chunk (tt direction)
      int phys = ck ^ (cl & 15);
      uint4 v = *(const uint4*)(smem + cl * 128 + phys * 8);
      *(uint4*)(vt + ((size_t)b * CC + n0 + cl) * TT + tt0 + ck * 8) = v;
    }
  }
}

// ---------------------------------------------------------------------------
// Kernel 4: S = q k^T (scale folded into q), causal mask + (==0 -> -inf),
// stored fp16.  1D grid of 544 LIVE lower-tri blocks = 8 XCD chunks x 68;
// triangular decode (guarded sqrt).  Same-ti blocks consecutive -> q-tile
// L2 reuse.
// ---------------------------------------------------------------------------
__global__ __launch_bounds__(256, 4) void s_gemm_kernel(
    const bf16_t* __restrict__ qb, const bf16_t* __restrict__ kb,
    _Float16* __restrict__ S) {
  __shared__ bf16_t As0[4096], As1[4096], Bs0[4096], Bs1[4096];
  int bid = blockIdx.x;
  int work = (bid & 7) * 68 + (bid >> 3);  // 544 = 8 * 68 (bijective)
  int b = work / 136;
  int t = work - b * 136;
  int ti = (int)((sqrtf(8.f * (float)t + 1.f) - 1.f) * 0.5f);
  while ((ti + 1) * (ti + 2) / 2 <= t) ++ti;  // guard fp rounding
  while (ti * (ti + 1) / 2 > t) --ti;
  int tj = t - ti * (ti + 1) / 2;
  int m0 = ti * 128, n0 = tj * 128;

  f32x4 acc[4][4];
#pragma unroll
  for (int i = 0; i < 4; ++i)
#pragma unroll
    for (int j = 0; j < 4; ++j) acc[i][j] = (f32x4){0.f, 0.f, 0.f, 0.f};

  const bf16_t* A = qb + ((size_t)b * TT + m0) * CC;
  const bf16_t* B = kb + ((size_t)b * TT + n0) * CC;
  gemm_core(A, CC, B, CC, CC / 32, As0, As1, Bs0, Bs1, acc);

  _Float16* Sb = S + (size_t)b * TT * TT;
  int l = threadIdx.x & 63, w = threadIdx.x >> 6;
  int wr = (w >> 1) * 64, wc = (w & 1) * 64;
#pragma unroll
  for (int mi = 0; mi < 4; ++mi) {
#pragma unroll
    for (int ni = 0; ni < 4; ++ni) {
      int j = n0 + wc + ni * 16 + (l & 15);
      int ibase = m0 + wr + mi * 16 + (l >> 4) * 4;
#pragma unroll
      for (int r = 0; r < 4; ++r) {
        int i = ibase + r;
        float v = acc[mi][ni][r];
        if (j > i || v == 0.0f) v = -INFINITY;  // causal + reference quirk
        Sb[(size_t)i * TT + j] = (_Float16)v;
      }
    }
  }
}

// ---------------------------------------------------------------------------
// Kernel 5: rowstat+normalize, wave-per-row (no LDS, no barriers).
// Block = 4 waves = 4 rows.  Per row: max M, L = sum exp(s-M); writes
// P = exp(s-M)/L as bf16 up to the 128-padded causal length.
// Lane l covers chunks {l, l+64, l+128, l+192} of 8 fp16 each.
// ---------------------------------------------------------------------------
__global__ __launch_bounds__(256) void rowstat_kernel(
    const _Float16* __restrict__ S, bf16_t* __restrict__ P) {
  int g = blockIdx.x * 4 + (threadIdx.x >> 6);  // global row id
  int b = g >> 11;
  int row = g & (TT - 1);
  int l = threadIdx.x & 63;
  const _Float16* s = S + ((size_t)b * TT + row) * TT;
  bf16_t* p = P + ((size_t)b * TT + row) * TT;
  int pe = ((row >> 7) + 1) << 7;  // padded causal length, multiple of 128

  float f[4][8];
#pragma unroll
  for (int c = 0; c < 4; ++c) {
    int j = (c * 64 + l) * 8;
    if (j < pe) {
      half8 h = *(const half8*)(s + j);
#pragma unroll
      for (int k = 0; k < 8; ++k) f[c][k] = (float)h[k];
    } else {
#pragma unroll
      for (int k = 0; k < 8; ++k) f[c][k] = -INFINITY;
    }
  }

  float m = f[0][0];
#pragma unroll
  for (int c = 0; c < 4; ++c)
#pragma unroll
    for (int k = 0; k < 8; ++k) m = fmaxf(m, f[c][k]);
#pragma unroll
  for (int off = 32; off > 0; off >>= 1) m = fmaxf(m, __shfl_xor(m, off));

  float e[4][8];
  float sum = 0.f;
#pragma unroll
  for (int c = 0; c < 4; ++c)
#pragma unroll
    for (int k = 0; k < 8; ++k) {
      e[c][k] = __expf(f[c][k] - m);  // exp(-inf)=0 for masked slots
      sum += e[c][k];
    }
#pragma unroll
  for (int off = 32; off > 0; off >>= 1) sum += __shfl_xor(sum, off);
  float inv = 1.0f / sum;

#pragma unroll
  for (int c = 0; c < 4; ++c) {
    int j = (c * 64 + l) * 8;
    if (j < pe) {
      bf16x8 o;
#pragma unroll
      for (int k = 0; k < 8; ++k) o[k] = (bf16_t)(e[c][k] * inv);
      *(bf16x8*)(p + j) = o;
    }
  }
}

// ---------------------------------------------------------------------------
// Kernel 6: O = P @ V   (A = P row-major [T][T], Bt = v^T [B][H][T]).
// 1D grid of 384 = 8 XCD chunks x 48.  Within a chunk: nj fastest (A-tile
// reuse), ti from the balance-paired permutation {15,0,14,1,...} so every
// chunk gets equal causal K work; heavy tiles lead each chunk.
// K-loop truncated at the causal boundary.
// ---------------------------------------------------------------------------
__global__ __launch_bounds__(256, 4) void o_gemm_kernel(
    const bf16_t* __restrict__ P, const bf16_t* __restrict__ vt,
    float* __restrict__ out) {
  __shared__ bf16_t As0[4096], As1[4096], Bs0[4096], Bs1[4096];
  int bid = blockIdx.x;
  int work = (bid & 7) * 48 + (bid >> 3);  // 384 = 8 * 48 (bijective)
  int b = work / 96;
  int rw = work - b * 96;
  int i = rw / 6, nj = rw % 6;
  int ti = (i & 1) ? ((i - 1) >> 1) : (15 - (i >> 1));  // 15,0,14,1,...,8,7
  int m0 = ti * 128, n0 = nj * 128;

  f32x4 acc[4][4];
#pragma unroll
  for (int ii = 0; ii < 4; ++ii)
#pragma unroll
    for (int j = 0; j < 4; ++j) acc[ii][j] = (f32x4){0.f, 0.f, 0.f, 0.f};

  const bf16_t* A = P + ((size_t)b * TT + m0) * TT;
  const bf16_t* B = vt + ((size_t)b * CC + n0) * TT;
  gemm_core(A, TT, B, TT, (ti + 1) * 4, As0, As1, Bs0, Bs1, acc);

  float* Ob = out + (size_t)b * TT * CC;
  int l = threadIdx.x & 63, w = threadIdx.x >> 6;
  int wr = (w >> 1) * 64, wc = (w & 1) * 64;
#pragma unroll
  for (int mi = 0; mi < 4; ++mi) {
#pragma unroll
    for (int ni = 0; ni < 4; ++ni) {
      int col = n0 + wc + ni * 16 + (l & 15);
      int ibase = m0 + wr + mi * 16 + (l >> 4) * 4;
#pragma unroll
      for (int r = 0; r < 4; ++r)
        Ob[(size_t)(ibase + r) * CC + col] = acc[mi][ni][r];
    }
  }
}

// ---------------------------------------------------------------------------
extern "C" void kernel_launch(void* const* d_in, const int* in_sizes, int n_in,
                              void* d_out, int out_size, void* d_ws,
                              size_t ws_size, hipStream_t stream) {
  const float* x = (const float*)d_in[0];
  const float* Wq = (const float*)d_in[1];
  const float* bq = (const float*)d_in[2];
  const float* Wk = (const float*)d_in[3];
  const float* bk = (const float*)d_in[4];
  const float* Wv = (const float*)d_in[5];
  const float* bv = (const float*)d_in[6];
  float* out = (float*)d_out;

  char* ws = (char*)d_ws;
  size_t off = 0;
  auto carve = [&](size_t bytes) -> char* {
    char* p = ws + off;
    off += (bytes + 255) & ~(size_t)255;
    return p;
  };
  const size_t M = (size_t)BB * TT;  // 8192
  bf16_t* xbf = (bf16_t*)carve(M * CC * 2);            // 12.6 MB
  bf16_t* wt  = (bf16_t*)carve(3ull * CC * CC * 2);    // 3.5 MB
  bf16_t* qb  = (bf16_t*)carve(M * CC * 2);            // 12.6 MB
  bf16_t* kb  = (bf16_t*)carve(M * CC * 2);            // 12.6 MB
  bf16_t* vt  = (bf16_t*)carve(M * CC * 2);            // 12.6 MB (as [B][H][T])
  _Float16* S = (_Float16*)carve((size_t)BB * TT * TT * 2);  // 33.5 MB
  bf16_t* P   = (bf16_t*)carve((size_t)BB * TT * TT * 2);    // 33.5 MB
  (void)off; (void)ws_size;

  // 1+2: input prep
  cast_x_kernel<<<(M * CC / 8 + 255) / 256, 256, 0, stream>>>(x, xbf);
  transpose_w_kernel<<<dim3(CC / 32, CC / 32, 3), dim3(32, 8, 1), 0, stream>>>(
      Wq, Wk, Wv, wt);
  // 3: q,k,v
  qkv_gemm_kernel<<<1152, 256, 0, stream>>>(xbf, wt, bq, bk, bv, qb, kb, vt);
  // 4: S = q k^T (lower-tri blocks, fp16)
  s_gemm_kernel<<<544, 256, 0, stream>>>(qb, kb, S);
  // 5: softmax rows -> P (bf16, zero-padded)
  rowstat_kernel<<<BB * TT / 4, 256, 0, stream>>>(S, P);
  // 6: O = P V
  o_gemm_kernel<<<384, 256, 0, stream>>>(P, vt, out);
}